// Round 7
// baseline (1567.527 us; speedup 1.0000x reference)
//
#include <hip/hip_runtime.h>
#include <math.h>

#define NB   8
#define NC   192
#define NPIX 3136
#define NBLK 49            // 3136/64 j-tiles (and i-tiles for knn)
#define SPLIT 8            // j-range splits per i-tile
#define GRID_LL (NB*98)    // 784: M-tile 32
#define GRID_KNN (NB*SPLIT*NBLK)   // 3136
#define GRID_MSG (NB*196)  // 1568: 16 rows per block
#define FINF 3.4e38f

__device__ __forceinline__ float gelu_f(float x){
    float u = 0.7978845608028654f * (x + 0.044715f * x * x * x);
    return 0.5f * x * (1.0f + tanhf(u));
}

// lexicographic (d, idx) less-than
#define LESS9(da,ia,db,ib) ((da) < (db) || ((da) == (db) && (ia) < (ib)))
// conditional swap keeping (a,ia) <= (b,ib); pure ?: selects, register-resident
#define CSW9(a,ia,b,ib) { bool sw_ = LESS9(b,ib,a,ia); float tf_=(a); int ti_=(ia); \
    (a) = sw_? (b) : (a); (ia) = sw_? (ib) : (ia); (b) = sw_? tf_ : (b); (ib) = sw_? ti_ : (ib); }

// top-9 smallest (d, idx), all state in named scalars -> VGPRs (no arrays, no scratch)
struct Top9 {
    float d0,d1,d2,d3,d4,d5,d6,d7,d8;
    int   j0,j1,j2,j3,j4,j5,j6,j7,j8;
    __device__ __forceinline__ void init(){
        d0=d1=d2=d3=d4=d5=d6=d7=d8=FINF;
        j0=j1=j2=j3=j4=j5=j6=j7=j8=0x7FFFFFFF;
    }
    __device__ __forceinline__ void insert(float nd, int ni){
        if (!LESS9(nd, ni, d8, j8)) return;
        d8 = nd; j8 = ni;
        CSW9(d7,j7,d8,j8);
        CSW9(d6,j6,d7,j7);
        CSW9(d5,j5,d6,j6);
        CSW9(d4,j4,d5,j5);
        CSW9(d3,j3,d4,j4);
        CSW9(d2,j2,d3,j3);
        CSW9(d1,j1,d2,j2);
        CSW9(d0,j0,d1,j1);
    }
};

// ---------------------------------------------------------------------------
// Fused GEMM + lorentz_linear. Tile 32 rows x 192 cols, 256 thr:
// tx (0..15) covers 12 cols each, ty (0..15) covers 2 rows each.
// ---------------------------------------------------------------------------
template<int K, bool IN_X, bool ADD_X, bool ADD_RM, bool OUT_T>
__global__ __launch_bounds__(256, 4) void ll_kernel(
    const float* __restrict__ Ain, int in_stride,
    const float* __restrict__ Wt,     // [NC, K] row-major
    const float* __restrict__ bias,   // [NC]
    const float* __restrict__ sptr,   // scalar log_scale
    const float* __restrict__ Xres,   // x (B,C,N) residual, if ADD_X
    const float* __restrict__ Rrm, int r_stride,  // row-major residual, if ADD_RM
    float* __restrict__ Out, int out_stride)
{
    __shared__ float lA[32*36];    // [kk][mm], pad 36
    __shared__ float lW[32*196];   // [kk][nn], pad 196

    const int tid = threadIdx.x;
    const int tx = tid & 15, ty = tid >> 4;
    const int bid = blockIdx.x;
    const int b  = bid / 98;
    const int n0 = (bid % 98) * 32;
    const int row0 = b * NPIX + n0;

    float acc[2][12];
    #pragma unroll
    for (int mi = 0; mi < 2; ++mi)
        #pragma unroll
        for (int j = 0; j < 12; ++j) acc[mi][j] = 0.f;

    for (int kt = 0; kt < K/32; ++kt){
        // ---- stage A (gelu applied here): 32k x 32m ----
        if (IN_X){
            int kk = tid >> 3;
            int m4 = (tid & 7) * 4;
            float4 v = *(const float4*)&Ain[(size_t)(b*NC + kt*32 + kk)*NPIX + n0 + m4];
            v.x = gelu_f(v.x); v.y = gelu_f(v.y); v.z = gelu_f(v.z); v.w = gelu_f(v.w);
            *(float4*)&lA[kk*36 + m4] = v;
        } else {
            int mm = tid >> 3;
            int k4 = (tid & 7) * 4;
            float4 v = *(const float4*)&Ain[(size_t)(row0 + mm)*in_stride + kt*32 + k4];
            v.x = gelu_f(v.x); v.y = gelu_f(v.y); v.z = gelu_f(v.z); v.w = gelu_f(v.w);
            lA[(k4+0)*36 + mm] = v.x; lA[(k4+1)*36 + mm] = v.y;
            lA[(k4+2)*36 + mm] = v.z; lA[(k4+3)*36 + mm] = v.w;
        }
        // ---- stage W (transposed): 32k x 192n ----
        #pragma unroll
        for (int r = 0; r < 6; ++r){
            int e  = tid + r*256;
            int nn = e >> 3;
            int k4 = (e & 7) * 4;
            float4 v = *(const float4*)&Wt[nn*K + kt*32 + k4];
            lW[(k4+0)*196 + nn] = v.x; lW[(k4+1)*196 + nn] = v.y;
            lW[(k4+2)*196 + nn] = v.z; lW[(k4+3)*196 + nn] = v.w;
        }
        __syncthreads();
        #pragma unroll
        for (int kk = 0; kk < 32; ++kk){
            float2 a2 = *(const float2*)&lA[kk*36 + ty*2];
            float4 w0 = *(const float4*)&lW[kk*196 + tx*12];
            float4 w1 = *(const float4*)&lW[kk*196 + tx*12 + 4];
            float4 w2 = *(const float4*)&lW[kk*196 + tx*12 + 8];
            float aw[2]  = {a2.x, a2.y};
            float wv[12] = {w0.x,w0.y,w0.z,w0.w, w1.x,w1.y,w1.z,w1.w, w2.x,w2.y,w2.z,w2.w};
            #pragma unroll
            for (int mi = 0; mi < 2; ++mi)
                #pragma unroll
                for (int j = 0; j < 12; ++j)
                    acc[mi][j] = fmaf(aw[mi], wv[j], acc[mi][j]);
        }
        __syncthreads();
    }

    // ---- lorentz epilogue ----
    const int lane = tid & 63;
    float es = expf(sptr[0]);
    float bv[12];
    #pragma unroll
    for (int q = 0; q < 3; ++q){
        float4 t4 = *(const float4*)&bias[tx*12 + q*4];
        bv[q*4+0] = t4.x; bv[q*4+1] = t4.y; bv[q*4+2] = t4.z; bv[q*4+3] = t4.w;
    }
    #pragma unroll
    for (int mi = 0; mi < 2; ++mi){
        float part = 0.f;
        #pragma unroll
        for (int j = 0; j < 12; ++j){
            float y = acc[mi][j] + bv[j];
            acc[mi][j] = y;
            if (!(tx == 0 && j == 0)) part += y * y;   // exclude global col 0
        }
        #pragma unroll
        for (int m = 1; m < 16; m <<= 1) part += __shfl_xor(part, m, 64);
        float y0   = __shfl(acc[mi][0], lane & 48, 64);   // col-0 value of this row
        float tval = es / (1.f + expf(-y0)) + 1.1f;
        float denom = fmaxf(part, 1e-8f);
        float sca  = (tval*tval - 1.f) / denom;
        float sqs  = sqrtf(sca);
        #pragma unroll
        for (int j = 0; j < 12; ++j){
            float o = acc[mi][j] * sqs;
            if (tx == 0 && j == 0) o = tval;
            acc[mi][j] = o;
        }
    }
    if (ADD_X){
        #pragma unroll
        for (int j = 0; j < 12; ++j){
            int c = tx*12 + j;
            float2 xv = *(const float2*)&Xres[(size_t)(b*NC + c)*NPIX + n0 + ty*2];
            acc[0][j] += xv.x; acc[1][j] += xv.y;
        }
    }
    if (ADD_RM){
        #pragma unroll
        for (int mi = 0; mi < 2; ++mi){
            #pragma unroll
            for (int q = 0; q < 3; ++q){
                float4 rv = *(const float4*)&Rrm[(size_t)(row0 + ty*2 + mi)*r_stride + tx*12 + q*4];
                acc[mi][q*4+0] += rv.x; acc[mi][q*4+1] += rv.y;
                acc[mi][q*4+2] += rv.z; acc[mi][q*4+3] += rv.w;
            }
        }
    }
    if (OUT_T){
        #pragma unroll
        for (int j = 0; j < 12; ++j){
            int c = tx*12 + j;
            *(float2*)&Out[(size_t)(b*NC + c)*NPIX + n0 + ty*2] = make_float2(acc[0][j], acc[1][j]);
        }
    } else {
        #pragma unroll
        for (int mi = 0; mi < 2; ++mi){
            #pragma unroll
            for (int q = 0; q < 3; ++q){
                float4 o = make_float4(acc[mi][q*4+0], acc[mi][q*4+1], acc[mi][q*4+2], acc[mi][q*4+3]);
                *(float4*)&Out[(size_t)(row0 + ty*2 + mi)*out_stride + tx*12 + q*4] = o;
            }
        }
    }
}

// ---------------------------------------------------------------------------
// Row squared-norms of xn1 (stored in H cols [0,192), stride 384)
// ---------------------------------------------------------------------------
__global__ __launch_bounds__(256) void sq_kernel(const float* __restrict__ H, float* __restrict__ SQ){
    int tid = threadIdx.x;
    int row = blockIdx.x * 64 + (tid >> 2);
    const float* p = H + (size_t)row*384 + (tid & 3)*48;
    float s = 0.f;
    #pragma unroll
    for (int q = 0; q < 12; ++q){
        float4 v = *(const float4*)&p[q*4];
        s = fmaf(v.x, v.x, fmaf(v.y, v.y, fmaf(v.z, v.z, fmaf(v.w, v.w, s))));
    }
    s += __shfl_xor(s, 1, 64);
    s += __shfl_xor(s, 2, 64);
    if ((tid & 3) == 0) SQ[row] = s;
}

// XOR-swizzled LDS float index: row-stride 64, quad permuted by (row&15)
__device__ __forceinline__ int swz(int r, int cq){
    return r*64 + ((cq ^ (r & 15)) << 2);
}

// ---------------------------------------------------------------------------
// Partial kNN(top-9). Block = 64 i-rows x (subset of j-tiles). 256 thr =
// 32 ty (2 i-rows: ty, ty+32) x 8 tx (8 j: tx+8*jj). c chunked x64.
// bid = (sp*NBLK + itile)*8 + b  -> XCD round-robin keeps one batch per XCD.
// waves_per_eu(2): regalloc budget 256 VGPR -> top-9 state stays in registers.
// ---------------------------------------------------------------------------
__global__ __launch_bounds__(256) __attribute__((amdgpu_waves_per_eu(2))) void knn_kernel(
    const float* __restrict__ H, const float* __restrict__ SQ,
    float* __restrict__ PD, int* __restrict__ PI)
{
    __shared__ float lXi[4096];
    __shared__ float lXj[4096];
    __shared__ float lSq[64];

    const int tid = threadIdx.x;
    const int tx = tid & 7, ty = tid >> 3;
    const int bid = blockIdx.x;
    const int b   = bid & 7;                // XCD-aligned batch
    const int t2  = bid >> 3;               // sp*NBLK + itile
    const int itile = t2 % NBLK;
    const int sp  = t2 / NBLK;
    const int i0  = itile * 64;
    const int base = b * NPIX;
    const int jt0 = (sp * NBLK) / SPLIT;
    const int jt1 = ((sp + 1) * NBLK) / SPLIT;

    Top9 t0, t1;
    t0.init(); t1.init();

    for (int jt = jt0; jt < jt1; ++jt){
        int j0 = jt * 64;
        float dac[2][8];
        #pragma unroll
        for (int mi = 0; mi < 2; ++mi)
            #pragma unroll
            for (int jj = 0; jj < 8; ++jj) dac[mi][jj] = 0.f;

        for (int ch = 0; ch < 3; ++ch){
            __syncthreads();
            #pragma unroll
            for (int r = 0; r < 4; ++r){
                int e  = tid + r*256;          // 1024 float4 = 64 rows x 16 quads
                int rw = e >> 4;
                int q  = e & 15;
                float4 vi = *(const float4*)&H[(size_t)(base + i0 + rw)*384 + ch*64 + q*4];
                *(float4*)&lXi[swz(rw, q)] = vi;
                float4 vj = *(const float4*)&H[(size_t)(base + j0 + rw)*384 + ch*64 + q*4];
                *(float4*)&lXj[swz(rw, q)] = vj;
            }
            if (ch == 0 && tid < 16){
                float4 sv = *(const float4*)&SQ[base + j0 + tid*4];
                *(float4*)&lSq[tid*4] = sv;
            }
            __syncthreads();
            #pragma unroll
            for (int cq = 0; cq < 16; ++cq){
                float4 a0 = *(const float4*)&lXi[swz(ty,      cq)];
                float4 a1 = *(const float4*)&lXi[swz(ty + 32, cq)];
                #pragma unroll
                for (int jj = 0; jj < 8; ++jj){
                    float4 w = *(const float4*)&lXj[swz(tx + 8*jj, cq)];
                    dac[0][jj] = fmaf(a0.x, w.x, fmaf(a0.y, w.y, fmaf(a0.z, w.z, fmaf(a0.w, w.w, dac[0][jj]))));
                    dac[1][jj] = fmaf(a1.x, w.x, fmaf(a1.y, w.y, fmaf(a1.z, w.z, fmaf(a1.w, w.w, dac[1][jj]))));
                }
            }
        }
        #pragma unroll
        for (int jj = 0; jj < 8; ++jj){
            int j = j0 + tx + 8*jj;
            float sqj = lSq[tx + 8*jj];
            float dd0 = fmaf(-2.f, dac[0][jj], sqj);
            t0.insert(dd0, j);
            float dd1 = fmaf(-2.f, dac[1][jj], sqj);
            t1.insert(dd1, j);
        }
    }

    // ---- merge 8 tx-stripes per row; two statically-separate halves ----
    float* smd = lXi;
    int*   smi = (int*)lXj;

    // rows 0..31 (i = i0 + ty)
    __syncthreads();
    {
        int s9 = (ty*8 + tx)*9;
        smd[s9+0]=t0.d0; smd[s9+1]=t0.d1; smd[s9+2]=t0.d2; smd[s9+3]=t0.d3; smd[s9+4]=t0.d4;
        smd[s9+5]=t0.d5; smd[s9+6]=t0.d6; smd[s9+7]=t0.d7; smd[s9+8]=t0.d8;
        smi[s9+0]=t0.j0; smi[s9+1]=t0.j1; smi[s9+2]=t0.j2; smi[s9+3]=t0.j3; smi[s9+4]=t0.j4;
        smi[s9+5]=t0.j5; smi[s9+6]=t0.j6; smi[s9+7]=t0.j7; smi[s9+8]=t0.j8;
    }
    __syncthreads();
    if (tid < 32){
        Top9 m; m.init();
        for (int t = 0; t < 8; ++t){
            int s9 = (tid*8 + t)*9;
            #pragma unroll
            for (int e = 0; e < 9; ++e) m.insert(smd[s9+e], smi[s9+e]);
        }
        size_t po = ((size_t)bid*64 + tid)*9;
        PD[po+0]=m.d0; PD[po+1]=m.d1; PD[po+2]=m.d2; PD[po+3]=m.d3; PD[po+4]=m.d4;
        PD[po+5]=m.d5; PD[po+6]=m.d6; PD[po+7]=m.d7; PD[po+8]=m.d8;
        PI[po+0]=m.j0; PI[po+1]=m.j1; PI[po+2]=m.j2; PI[po+3]=m.j3; PI[po+4]=m.j4;
        PI[po+5]=m.j5; PI[po+6]=m.j6; PI[po+7]=m.j7; PI[po+8]=m.j8;
    }

    // rows 32..63 (i = i0 + 32 + ty)
    __syncthreads();
    {
        int s9 = (ty*8 + tx)*9;
        smd[s9+0]=t1.d0; smd[s9+1]=t1.d1; smd[s9+2]=t1.d2; smd[s9+3]=t1.d3; smd[s9+4]=t1.d4;
        smd[s9+5]=t1.d5; smd[s9+6]=t1.d6; smd[s9+7]=t1.d7; smd[s9+8]=t1.d8;
        smi[s9+0]=t1.j0; smi[s9+1]=t1.j1; smi[s9+2]=t1.j2; smi[s9+3]=t1.j3; smi[s9+4]=t1.j4;
        smi[s9+5]=t1.j5; smi[s9+6]=t1.j6; smi[s9+7]=t1.j7; smi[s9+8]=t1.j8;
    }
    __syncthreads();
    if (tid < 32){
        Top9 m; m.init();
        for (int t = 0; t < 8; ++t){
            int s9 = (tid*8 + t)*9;
            #pragma unroll
            for (int e = 0; e < 9; ++e) m.insert(smd[s9+e], smi[s9+e]);
        }
        size_t po = ((size_t)bid*64 + 32 + tid)*9;
        PD[po+0]=m.d0; PD[po+1]=m.d1; PD[po+2]=m.d2; PD[po+3]=m.d3; PD[po+4]=m.d4;
        PD[po+5]=m.d5; PD[po+6]=m.d6; PD[po+7]=m.d7; PD[po+8]=m.d8;
        PI[po+0]=m.j0; PI[po+1]=m.j1; PI[po+2]=m.j2; PI[po+3]=m.j3; PI[po+4]=m.j4;
        PI[po+5]=m.j5; PI[po+6]=m.j6; PI[po+7]=m.j7; PI[po+8]=m.j8;
    }
}

// ---------------------------------------------------------------------------
// Merge SPLIT partial top-9 lists per row, then gather max-message.
// Block = 16 rows; msg written to H cols [192,384).
// PD/PI layout: partial-block bid = (sp*NBLK + itile)*8 + b, 64 rows each.
// ---------------------------------------------------------------------------
__global__ __launch_bounds__(256) void merge_msg_kernel(
    const float* __restrict__ H, const float* __restrict__ PD, const int* __restrict__ PI,
    float* __restrict__ Hout)
{
    __shared__ int fidx[16*9];
    const int tid = threadIdx.x;
    const int bid = blockIdx.x;
    const int b  = bid / 196;
    const int i0 = (bid % 196) * 16;
    const int base = b * NPIX;

    if (tid < 16){
        int i = i0 + tid;
        int itile = i >> 6, rl = i & 63;
        Top9 m; m.init();
        for (int sp = 0; sp < SPLIT; ++sp){
            size_t po = ((size_t)((sp*NBLK + itile)*8 + b)*64 + rl)*9;
            #pragma unroll
            for (int e = 0; e < 9; ++e) m.insert(PD[po + e], PI[po + e]);
        }
        fidx[tid*9+0]=m.j0; fidx[tid*9+1]=m.j1; fidx[tid*9+2]=m.j2; fidx[tid*9+3]=m.j3;
        fidx[tid*9+4]=m.j4; fidx[tid*9+5]=m.j5; fidx[tid*9+6]=m.j6; fidx[tid*9+7]=m.j7;
        fidx[tid*9+8]=m.j8;
    }
    __syncthreads();

    int rl = tid >> 4, part = tid & 15;       // 16 rows x 16 col-parts (12 cols each)
    int i = i0 + rl;
    int nbr[9];
    #pragma unroll
    for (int e = 0; e < 9; ++e) nbr[e] = fidx[rl*9 + e];
    const float* pi = H + (size_t)(base + i)*384 + part*12;
    float* po = Hout + (size_t)(base + i)*384 + 192 + part*12;
    #pragma unroll
    for (int q = 0; q < 3; ++q){
        float4 mv = make_float4(-FINF, -FINF, -FINF, -FINF);
        #pragma unroll
        for (int e = 0; e < 9; ++e){
            float4 v = *(const float4*)&H[(size_t)(base + nbr[e])*384 + part*12 + q*4];
            mv.x = fmaxf(mv.x, v.x); mv.y = fmaxf(mv.y, v.y);
            mv.z = fmaxf(mv.z, v.z); mv.w = fmaxf(mv.w, v.w);
        }
        float4 xi = *(const float4*)&pi[q*4];
        *(float4*)&po[q*4] = make_float4(mv.x - xi.x, mv.y - xi.y, mv.z - xi.z, mv.w - xi.w);
    }
}

extern "C" void kernel_launch(void* const* d_in, const int* in_sizes, int n_in,
                              void* d_out, int out_size, void* d_ws, size_t ws_size,
                              hipStream_t stream)
{
    const float* x  = (const float*)d_in[0];
    const float* W1 = (const float*)d_in[1];
    const float* b1 = (const float*)d_in[2];
    const float* s1 = (const float*)d_in[3];
    const float* W2 = (const float*)d_in[4];
    const float* b2 = (const float*)d_in[5];
    const float* s2 = (const float*)d_in[6];
    const float* Wg = (const float*)d_in[7];
    const float* bg = (const float*)d_in[8];
    const float* sg = (const float*)d_in[9];
    const float* W3 = (const float*)d_in[10];
    const float* b3 = (const float*)d_in[11];
    const float* s3 = (const float*)d_in[12];
    const float* W4 = (const float*)d_in[13];
    const float* b4 = (const float*)d_in[14];
    const float* s4 = (const float*)d_in[15];

    float* H  = (float*)d_ws;                       // [25088][384]: xn1 | msg
    float* T1 = H  + (size_t)25088*384;             // LL1 out (dead before partials reuse); later LL3 out
    float* X2 = T1 + (size_t)25088*192;             // graph-conv out (xn2)
    float* SQ = X2 + (size_t)25088*192;             // row sq-norms
    float* PD = T1;                                 // partial dists  (GRID_KNN*64*9 = 1.81M floats)
    int*   PI = (int*)(T1 + (size_t)GRID_KNN*64*9); // partial indices (1.81M ints)
    float* out = (float*)d_out;

    // ffn_lorentz #1
    ll_kernel<192, true , false, false, false><<<GRID_LL, 256, 0, stream>>>(x, 0,   W1, b1, s1, nullptr, nullptr, 0, T1, 192);
    ll_kernel<192, false, true , false, false><<<GRID_LL, 256, 0, stream>>>(T1, 192, W2, b2, s2, x,      nullptr, 0, H, 384);
    // graph conv
    sq_kernel<<<NB*NBLK, 256, 0, stream>>>(H, SQ);
    knn_kernel<<<GRID_KNN, 256, 0, stream>>>(H, SQ, PD, PI);
    merge_msg_kernel<<<GRID_MSG, 256, 0, stream>>>(H, PD, PI, H);
    ll_kernel<384, false, false, false, false><<<GRID_LL, 256, 0, stream>>>(H, 384,  Wg, bg, sg, nullptr, nullptr, 0, X2, 192);
    // ffn_lorentz #2 + final shortcut, transposed store
    ll_kernel<192, false, false, false, false><<<GRID_LL, 256, 0, stream>>>(X2, 192, W3, b3, s3, nullptr, nullptr, 0, T1, 192);
    ll_kernel<192, false, true , true , true ><<<GRID_LL, 256, 0, stream>>>(T1, 192, W4, b4, s4, x,      X2, 192, out, 0);
}

// Round 9
// 1194.195 us; speedup vs baseline: 1.3126x; 1.3126x over previous
//
#include <hip/hip_runtime.h>
#include <math.h>

#define NB   8
#define NC   192
#define NPIX 3136
#define NPAD 3200
#define GRID_LL (NB*98)    // 784: M-tile 32
#define NIT  25            // i-tiles of 128 over padded 3200
#define NSP  8
#define GRID_KNN (NB*NIT*NSP)   // 1600
#define GRID_MSG (NB*196)  // 1568: 16 rows per block
#define FINF 3.4e38f

typedef _Float16 f16x8 __attribute__((ext_vector_type(8)));
typedef float   f32x16 __attribute__((ext_vector_type(16)));

__device__ __forceinline__ float gelu_f(float x){
    float u = 0.7978845608028654f * (x + 0.044715f * x * x * x);
    return 0.5f * x * (1.0f + tanhf(u));
}

// ---------------- min-lex top9 (exact rescore) ----------------
#define LESS9(da,ia,db,ib) ((da) < (db) || ((da) == (db) && (ia) < (ib)))
#define CSW9(a,ia,b,ib) { bool sw_ = LESS9(b,ib,a,ia); float tf_=(a); int ti_=(ia); \
    (a) = sw_? (b) : (a); (ia) = sw_? (ib) : (ia); (b) = sw_? tf_ : (b); (ib) = sw_? ti_ : (ib); }

struct Top9 {
    float d0,d1,d2,d3,d4,d5,d6,d7,d8;
    int   j0,j1,j2,j3,j4,j5,j6,j7,j8;
    __device__ __forceinline__ void init(){
        d0=d1=d2=d3=d4=d5=d6=d7=d8=FINF;
        j0=j1=j2=j3=j4=j5=j6=j7=j8=0x7FFFFFFF;
    }
    __device__ __forceinline__ void insert(float nd, int ni){
        if (!LESS9(nd, ni, d8, j8)) return;
        d8 = nd; j8 = ni;
        CSW9(d7,j7,d8,j8); CSW9(d6,j6,d7,j7); CSW9(d5,j5,d6,j6); CSW9(d4,j4,d5,j5);
        CSW9(d3,j3,d4,j4); CSW9(d2,j2,d3,j3); CSW9(d1,j1,d2,j2); CSW9(d0,j0,d1,j1);
    }
};

// ---------------- max-e top12 (knn screen, named locals) ----------------
#define RANKB(ea,ja,eb,jb) ((ea) > (eb) || ((ea) == (eb) && (ja) < (jb)))
#define CSWM(a,ja,b,jb) { bool s_ = RANKB(b,jb,a,ja); float tf_=(a); int ti_=(ja); \
    (a) = s_? (b) : (a); (ja) = s_? (jb) : (ja); (b) = s_? tf_ : (b); (jb) = s_? ti_ : (jb); }
#define INSMAX(e_,j_) \
    if (RANKB(e_,j_,t_e11,t_n11)) { t_e11=(e_); t_n11=(j_); \
        CSWM(t_e10,t_n10,t_e11,t_n11); CSWM(t_e9,t_n9,t_e10,t_n10); CSWM(t_e8,t_n8,t_e9,t_n9); \
        CSWM(t_e7,t_n7,t_e8,t_n8); CSWM(t_e6,t_n6,t_e7,t_n7); CSWM(t_e5,t_n5,t_e6,t_n6); \
        CSWM(t_e4,t_n4,t_e5,t_n5); CSWM(t_e3,t_n3,t_e4,t_n4); CSWM(t_e2,t_n2,t_e3,t_n3); \
        CSWM(t_e1,t_n1,t_e2,t_n2); CSWM(t_e0,t_n0,t_e1,t_n1); }

#define SCREEN16(A) fmaxf(fmaxf(fmaxf(fmaxf(A[0],A[1]),fmaxf(A[2],A[3])),fmaxf(fmaxf(A[4],A[5]),fmaxf(A[6],A[7]))), \
                          fmaxf(fmaxf(fmaxf(A[8],A[9]),fmaxf(A[10],A[11])),fmaxf(fmaxf(A[12],A[13]),fmaxf(A[14],A[15]))))
#define IE(A,R) { float e_=A[R]; int j_= jb_ + (((R)&3) + 8*((R)>>2)); INSMAX(e_,j_); }
#define INSACC(A,JS) { float em_ = SCREEN16(A); if (em_ >= t_e11){ int jb_ = jg + (JS)*32 + 4*h; \
    IE(A,0) IE(A,1) IE(A,2) IE(A,3) IE(A,4) IE(A,5) IE(A,6) IE(A,7) \
    IE(A,8) IE(A,9) IE(A,10) IE(A,11) IE(A,12) IE(A,13) IE(A,14) IE(A,15) } }

#define MF(ACC,AO,BO) ACC = __builtin_amdgcn_mfma_f32_32x32x16_f16(AO,BO,ACC,0,0,0);
#define ZERO16 {0,0,0,0,0,0,0,0,0,0,0,0,0,0,0,0}

// ---------------------------------------------------------------------------
// Fused GEMM + lorentz_linear (unchanged).
// ---------------------------------------------------------------------------
template<int K, bool IN_X, bool ADD_X, bool ADD_RM, bool OUT_T>
__global__ __launch_bounds__(256, 4) void ll_kernel(
    const float* __restrict__ Ain, int in_stride,
    const float* __restrict__ Wt, const float* __restrict__ bias,
    const float* __restrict__ sptr, const float* __restrict__ Xres,
    const float* __restrict__ Rrm, int r_stride,
    float* __restrict__ Out, int out_stride)
{
    __shared__ float lA[32*36];
    __shared__ float lW[32*196];

    const int tid = threadIdx.x;
    const int tx = tid & 15, ty = tid >> 4;
    const int bid = blockIdx.x;
    const int b  = bid / 98;
    const int n0 = (bid % 98) * 32;
    const int row0 = b * NPIX + n0;

    float acc[2][12];
    #pragma unroll
    for (int mi = 0; mi < 2; ++mi)
        #pragma unroll
        for (int j = 0; j < 12; ++j) acc[mi][j] = 0.f;

    for (int kt = 0; kt < K/32; ++kt){
        if (IN_X){
            int kk = tid >> 3;
            int m4 = (tid & 7) * 4;
            float4 v = *(const float4*)&Ain[(size_t)(b*NC + kt*32 + kk)*NPIX + n0 + m4];
            v.x = gelu_f(v.x); v.y = gelu_f(v.y); v.z = gelu_f(v.z); v.w = gelu_f(v.w);
            *(float4*)&lA[kk*36 + m4] = v;
        } else {
            int mm = tid >> 3;
            int k4 = (tid & 7) * 4;
            float4 v = *(const float4*)&Ain[(size_t)(row0 + mm)*in_stride + kt*32 + k4];
            v.x = gelu_f(v.x); v.y = gelu_f(v.y); v.z = gelu_f(v.z); v.w = gelu_f(v.w);
            lA[(k4+0)*36 + mm] = v.x; lA[(k4+1)*36 + mm] = v.y;
            lA[(k4+2)*36 + mm] = v.z; lA[(k4+3)*36 + mm] = v.w;
        }
        #pragma unroll
        for (int r = 0; r < 6; ++r){
            int e  = tid + r*256;
            int nn = e >> 3;
            int k4 = (e & 7) * 4;
            float4 v = *(const float4*)&Wt[nn*K + kt*32 + k4];
            lW[(k4+0)*196 + nn] = v.x; lW[(k4+1)*196 + nn] = v.y;
            lW[(k4+2)*196 + nn] = v.z; lW[(k4+3)*196 + nn] = v.w;
        }
        __syncthreads();
        #pragma unroll
        for (int kk = 0; kk < 32; ++kk){
            float2 a2 = *(const float2*)&lA[kk*36 + ty*2];
            float4 w0 = *(const float4*)&lW[kk*196 + tx*12];
            float4 w1 = *(const float4*)&lW[kk*196 + tx*12 + 4];
            float4 w2 = *(const float4*)&lW[kk*196 + tx*12 + 8];
            float aw[2]  = {a2.x, a2.y};
            float wv[12] = {w0.x,w0.y,w0.z,w0.w, w1.x,w1.y,w1.z,w1.w, w2.x,w2.y,w2.z,w2.w};
            #pragma unroll
            for (int mi = 0; mi < 2; ++mi)
                #pragma unroll
                for (int j = 0; j < 12; ++j)
                    acc[mi][j] = fmaf(aw[mi], wv[j], acc[mi][j]);
        }
        __syncthreads();
    }

    const int lane = tid & 63;
    float es = expf(sptr[0]);
    float bv[12];
    #pragma unroll
    for (int q = 0; q < 3; ++q){
        float4 t4 = *(const float4*)&bias[tx*12 + q*4];
        bv[q*4+0] = t4.x; bv[q*4+1] = t4.y; bv[q*4+2] = t4.z; bv[q*4+3] = t4.w;
    }
    #pragma unroll
    for (int mi = 0; mi < 2; ++mi){
        float part = 0.f;
        #pragma unroll
        for (int j = 0; j < 12; ++j){
            float y = acc[mi][j] + bv[j];
            acc[mi][j] = y;
            if (!(tx == 0 && j == 0)) part += y * y;
        }
        #pragma unroll
        for (int m = 1; m < 16; m <<= 1) part += __shfl_xor(part, m, 64);
        float y0   = __shfl(acc[mi][0], lane & 48, 64);
        float tval = es / (1.f + expf(-y0)) + 1.1f;
        float denom = fmaxf(part, 1e-8f);
        float sca  = (tval*tval - 1.f) / denom;
        float sqs  = sqrtf(sca);
        #pragma unroll
        for (int j = 0; j < 12; ++j){
            float o = acc[mi][j] * sqs;
            if (tx == 0 && j == 0) o = tval;
            acc[mi][j] = o;
        }
    }
    if (ADD_X){
        #pragma unroll
        for (int j = 0; j < 12; ++j){
            int c = tx*12 + j;
            float2 xv = *(const float2*)&Xres[(size_t)(b*NC + c)*NPIX + n0 + ty*2];
            acc[0][j] += xv.x; acc[1][j] += xv.y;
        }
    }
    if (ADD_RM){
        #pragma unroll
        for (int mi = 0; mi < 2; ++mi){
            #pragma unroll
            for (int q = 0; q < 3; ++q){
                float4 rv = *(const float4*)&Rrm[(size_t)(row0 + ty*2 + mi)*r_stride + tx*12 + q*4];
                acc[mi][q*4+0] += rv.x; acc[mi][q*4+1] += rv.y;
                acc[mi][q*4+2] += rv.z; acc[mi][q*4+3] += rv.w;
            }
        }
    }
    if (OUT_T){
        #pragma unroll
        for (int j = 0; j < 12; ++j){
            int c = tx*12 + j;
            *(float2*)&Out[(size_t)(b*NC + c)*NPIX + n0 + ty*2] = make_float2(acc[0][j], acc[1][j]);
        }
    } else {
        #pragma unroll
        for (int mi = 0; mi < 2; ++mi){
            #pragma unroll
            for (int q = 0; q < 3; ++q){
                float4 o = make_float4(acc[mi][q*4+0], acc[mi][q*4+1], acc[mi][q*4+2], acc[mi][q*4+3]);
                *(float4*)&Out[(size_t)(row0 + ty*2 + mi)*out_stride + tx*12 + q*4] = o;
            }
        }
    }
}

// ---------------------------------------------------------------------------
// conv: H fp32 rows -> Xh/Xl fp16 hi/lo [8][3200][192], S2 packed(-sq/2 hi,lo),
// SQf fp32 row sq-norms. Pad rows: x=0, s2=-30000.
// ---------------------------------------------------------------------------
__device__ __forceinline__ unsigned pack2(float a, float b, unsigned &lo){
    union { _Float16 f; unsigned short u; } ha, hb, la, lb;
    ha.f = (_Float16)a; hb.f = (_Float16)b;
    float ra = a - (float)ha.f, rb = b - (float)hb.f;
    la.f = (_Float16)ra; lb.f = (_Float16)rb;
    lo = (unsigned)la.u | ((unsigned)lb.u << 16);
    return (unsigned)ha.u | ((unsigned)hb.u << 16);
}

__global__ __launch_bounds__(256) void conv_kernel(
    const float* __restrict__ H, unsigned short* __restrict__ Xh,
    unsigned short* __restrict__ Xl, unsigned* __restrict__ S2,
    float* __restrict__ SQf)
{
    const int tid = threadIdx.x;
    const int r = blockIdx.x*64 + (tid >> 2);
    const int b = r / NPAD, rl = r - b*NPAD;
    const int part = tid & 3;
    const size_t ob = ((size_t)b*NPAD + rl)*192 + part*48;

    if (rl < NPIX){
        const float* src = H + ((size_t)b*NPIX + rl)*384 + part*48;
        float s = 0.f;
        #pragma unroll
        for (int q = 0; q < 6; ++q){
            float4 v0 = *(const float4*)&src[q*8];
            float4 v1 = *(const float4*)&src[q*8 + 4];
            s = fmaf(v0.x,v0.x, fmaf(v0.y,v0.y, fmaf(v0.z,v0.z, fmaf(v0.w,v0.w, s))));
            s = fmaf(v1.x,v1.x, fmaf(v1.y,v1.y, fmaf(v1.z,v1.z, fmaf(v1.w,v1.w, s))));
            uint4 hv, lv;
            hv.x = pack2(v0.x, v0.y, lv.x);
            hv.y = pack2(v0.z, v0.w, lv.y);
            hv.z = pack2(v1.x, v1.y, lv.z);
            hv.w = pack2(v1.z, v1.w, lv.w);
            *(uint4*)&Xh[ob + q*8] = hv;
            *(uint4*)&Xl[ob + q*8] = lv;
        }
        s += __shfl_xor(s, 1, 64);
        s += __shfl_xor(s, 2, 64);
        if (part == 0){
            SQf[(size_t)b*NPIX + rl] = s;
            float s2 = -0.5f * s;
            union { _Float16 f; unsigned short u; } hh, ll;
            hh.f = (_Float16)s2;
            float rr = s2 - (float)hh.f;
            ll.f = (_Float16)rr;
            S2[(size_t)b*NPAD + rl] = (unsigned)hh.u | ((unsigned)ll.u << 16);
        }
    } else {
        uint4 z = make_uint4(0,0,0,0);
        #pragma unroll
        for (int q = 0; q < 6; ++q){
            *(uint4*)&Xh[ob + q*8] = z;
            *(uint4*)&Xl[ob + q*8] = z;
        }
        if (part == 0){
            union { _Float16 f; unsigned short u; } p;
            p.f = (_Float16)(-30000.0f);
            S2[(size_t)b*NPAD + rl] = (unsigned)p.u;
        }
    }
}

// ---------------------------------------------------------------------------
// MFMA kNN screen. Block: 4 waves, i-tile 128 (wave w: i-cols i0+w*32..+31).
// 3-pass fp16 hi/lo; e = dot - sq_j/2 via augmented channel. Lane owns i-col
// lane&31; top-12 max-e in named registers; lane pair merged by shfl; writes
// candidate INDICES only (exact rescore happens in merge_msg_kernel).
// ---------------------------------------------------------------------------
__global__ __launch_bounds__(256) __attribute__((amdgpu_waves_per_eu(2))) void knn_kernel(
    const unsigned short* __restrict__ Xh, const unsigned short* __restrict__ Xl,
    const unsigned* __restrict__ S2, int* __restrict__ PI)
{
    __shared__ uint4 lds[2048];   // Ah | Al | Bh | Bl; 128 rows x 4 quads, swizzled

    const int tid  = threadIdx.x;
    const int lane = tid & 63;
    const int w    = tid >> 6;
    const int l31  = lane & 31;
    const int h    = lane >> 5;
    const int bid  = blockIdx.x;
    const int b    = bid & 7;
    const int t2   = bid >> 3;
    const int itile = t2 >> 3;
    const int sp    = t2 & 7;
    const int i0    = itile * 128;
    const int g0 = (sp*25)/8, g1 = ((sp+1)*25)/8;
    const size_t rowb = (size_t)b * NPAD;

    float t_e0=-FINF,t_e1=-FINF,t_e2=-FINF,t_e3=-FINF,t_e4=-FINF,t_e5=-FINF,
          t_e6=-FINF,t_e7=-FINF,t_e8=-FINF,t_e9=-FINF,t_e10=-FINF,t_e11=-FINF;
    int   t_n0=0x7FFFFFFF,t_n1=0x7FFFFFFF,t_n2=0x7FFFFFFF,t_n3=0x7FFFFFFF,
          t_n4=0x7FFFFFFF,t_n5=0x7FFFFFFF,t_n6=0x7FFFFFFF,t_n7=0x7FFFFFFF,
          t_n8=0x7FFFFFFF,t_n9=0x7FFFFFFF,t_n10=0x7FFFFFFF,t_n11=0x7FFFFFFF;

    for (int g = g0; g < g1; ++g){
        const int jg = g*128;
        f32x16 acc0 = ZERO16, acc1 = ZERO16, acc2 = ZERO16, acc3 = ZERO16;

        for (int kc = 0; kc < 6; ++kc){
            __syncthreads();
            #pragma unroll
            for (int rr = 0; rr < 8; ++rr){
                int u   = tid + rr*256;
                int arr = u >> 9;
                int rs  = (u >> 2) & 127;
                int seg = u & 3;
                int row = (arr < 2) ? (jg + rs) : (i0 + rs);
                const unsigned short* sptr = (arr & 1) ? Xl : Xh;
                uint4 v = *(const uint4*)&sptr[(rowb + row)*192 + kc*32 + seg*8];
                lds[arr*512 + rs*4 + (seg ^ ((rs >> 1) & 3))] = v;
            }
            __syncthreads();
            #pragma unroll
            for (int ks = 0; ks < 2; ++ks){
                int kq  = ks*2 + h;
                int sw  = kq ^ ((l31 >> 1) & 3);
                int rb4 = l31*4 + sw;
                f16x8 bh = __builtin_bit_cast(f16x8, lds[1024 + w*128 + rb4]);
                f16x8 bl = __builtin_bit_cast(f16x8, lds[1536 + w*128 + rb4]);
                f16x8 a0h = __builtin_bit_cast(f16x8, lds[      0 + rb4]);
                f16x8 a0l = __builtin_bit_cast(f16x8, lds[512 +   0 + rb4]);
                MF(acc0, a0h, bh) MF(acc0, a0l, bh) MF(acc0, a0h, bl)
                f16x8 a1h = __builtin_bit_cast(f16x8, lds[      128 + rb4]);
                f16x8 a1l = __builtin_bit_cast(f16x8, lds[512 + 128 + rb4]);
                MF(acc1, a1h, bh) MF(acc1, a1l, bh) MF(acc1, a1h, bl)
                f16x8 a2h = __builtin_bit_cast(f16x8, lds[      256 + rb4]);
                f16x8 a2l = __builtin_bit_cast(f16x8, lds[512 + 256 + rb4]);
                MF(acc2, a2h, bh) MF(acc2, a2l, bh) MF(acc2, a2h, bl)
                f16x8 a3h = __builtin_bit_cast(f16x8, lds[      384 + rb4]);
                f16x8 a3l = __builtin_bit_cast(f16x8, lds[512 + 384 + rb4]);
                MF(acc3, a3h, bh) MF(acc3, a3l, bh) MF(acc3, a3h, bl)
            }
        }

        // k=192 channel: A = -sq_j/2 (hi/lo), B = 1 at k-elem 0 (h==0 lanes)
        {
            unsigned m  = (h == 0) ? 0xFFFFFFFFu : 0u;
            unsigned om = 0x3C00u & m;
            f16x8 one = __builtin_bit_cast(f16x8, make_uint4(om, 0, 0, 0));
            unsigned s0 = S2[rowb + jg +  0 + l31];
            unsigned s1 = S2[rowb + jg + 32 + l31];
            unsigned s2 = S2[rowb + jg + 64 + l31];
            unsigned s3 = S2[rowb + jg + 96 + l31];
            f16x8 a;
            a = __builtin_bit_cast(f16x8, make_uint4((s0 & 0xFFFFu) & m, 0,0,0)); MF(acc0, a, one)
            a = __builtin_bit_cast(f16x8, make_uint4((s0 >> 16)     & m, 0,0,0)); MF(acc0, a, one)
            a = __builtin_bit_cast(f16x8, make_uint4((s1 & 0xFFFFu) & m, 0,0,0)); MF(acc1, a, one)
            a = __builtin_bit_cast(f16x8, make_uint4((s1 >> 16)     & m, 0,0,0)); MF(acc1, a, one)
            a = __builtin_bit_cast(f16x8, make_uint4((s2 & 0xFFFFu) & m, 0,0,0)); MF(acc2, a, one)
            a = __builtin_bit_cast(f16x8, make_uint4((s2 >> 16)     & m, 0,0,0)); MF(acc2, a, one)
            a = __builtin_bit_cast(f16x8, make_uint4((s3 & 0xFFFFu) & m, 0,0,0)); MF(acc3, a, one)
            a = __builtin_bit_cast(f16x8, make_uint4((s3 >> 16)     & m, 0,0,0)); MF(acc3, a, one)
        }

        INSACC(acc0, 0)
        INSACC(acc1, 1)
        INSACC(acc2, 2)
        INSACC(acc3, 3)
    }

    // merge lane pair (same i-col, disjoint j rows)
    #define MRG(E,N) { float oe_ = __shfl(E, lane ^ 32, 64); int on_ = __shfl(N, lane ^ 32, 64); \
                       if (lane < 32) { INSMAX(oe_, on_) } }
    MRG(t_e0,t_n0) MRG(t_e1,t_n1) MRG(t_e2,t_n2) MRG(t_e3,t_n3) MRG(t_e4,t_n4) MRG(t_e5,t_n5)
    MRG(t_e6,t_n6) MRG(t_e7,t_n7) MRG(t_e8,t_n8) MRG(t_e9,t_n9) MRG(t_e10,t_n10) MRG(t_e11,t_n11)

    if (lane < 32){
        size_t po = ((size_t)(t2*8 + b)*128 + (size_t)w*32 + l31)*12;
        PI[po+ 0] = t_n0;  PI[po+ 1] = t_n1;  PI[po+ 2] = t_n2;  PI[po+ 3] = t_n3;
        PI[po+ 4] = t_n4;  PI[po+ 5] = t_n5;  PI[po+ 6] = t_n6;  PI[po+ 7] = t_n7;
        PI[po+ 8] = t_n8;  PI[po+ 9] = t_n9;  PI[po+10] = t_n10; PI[po+11] = t_n11;
    }
}

// ---------------------------------------------------------------------------
// Exact rescore of 96 candidates/row (fp32), top-9, then max-message.
// 16 rows/block; 16 threads per row rescore 6 candidates each.
// ---------------------------------------------------------------------------
__global__ __launch_bounds__(256) void merge_msg_kernel(
    const float* __restrict__ H, const float* __restrict__ SQf,
    const int* __restrict__ PI, float* __restrict__ Hout)
{
    __shared__ float liX[16*192];
    __shared__ float dc[16*96];
    __shared__ int   jc[16*96];
    __shared__ int   fidx[16*9];

    const int tid = threadIdx.x;
    const int bid = blockIdx.x;
    const int b  = bid / 196;
    const int i0 = (bid % 196) * 16;
    const int base = b * NPIX;

    // stage the 16 i-rows (first 192 cols of H)
    #pragma unroll
    for (int k = 0; k < 3; ++k){
        int f = tid + k*256;               // 768 float4
        int r = f / 48, c4 = f % 48;
        *(float4*)&liX[r*192 + c4*4] = *(const float4*)&H[(size_t)(base + i0 + r)*384 + c4*4];
    }
    __syncthreads();

    const int r = tid >> 4, s = tid & 15;
    const int i = i0 + r;
    const int itile = i >> 7, rl = i & 127;
    for (int c = 0; c < 6; ++c){
        int cand = s*6 + c;
        int sp = cand / 12, slot = cand - sp*12;
        int j = PI[((size_t)((itile*8 + sp)*8 + b)*128 + rl)*12 + slot];
        const float* hj = &H[(size_t)(base + j)*384];
        float dot = 0.f;
        for (int q = 0; q < 48; ++q){
            float4 xv = *(const float4*)&liX[r*192 + q*4];
            float4 yv = *(const float4*)&hj[q*4];
            dot = fmaf(xv.x,yv.x, fmaf(xv.y,yv.y, fmaf(xv.z,yv.z, fmaf(xv.w,yv.w, dot))));
        }
        dc[r*96 + cand] = SQf[base + j] - 2.f*dot;
        jc[r*96 + cand] = j;
    }
    __syncthreads();

    if (s == 0){
        Top9 m; m.init();
        for (int c = 0; c < 96; ++c) m.insert(dc[r*96 + c], jc[r*96 + c]);
        fidx[r*9+0]=m.j0; fidx[r*9+1]=m.j1; fidx[r*9+2]=m.j2; fidx[r*9+3]=m.j3;
        fidx[r*9+4]=m.j4; fidx[r*9+5]=m.j5; fidx[r*9+6]=m.j6; fidx[r*9+7]=m.j7;
        fidx[r*9+8]=m.j8;
    }
    __syncthreads();

    int rr = tid >> 4, part = tid & 15;
    int ii = i0 + rr;
    int nbr[9];
    #pragma unroll
    for (int e = 0; e < 9; ++e) nbr[e] = fidx[rr*9 + e];
    const float* pi = H + (size_t)(base + ii)*384 + part*12;
    float* po = Hout + (size_t)(base + ii)*384 + 192 + part*12;
    #pragma unroll
    for (int q = 0; q < 3; ++q){
        float4 mv = make_float4(-FINF, -FINF, -FINF, -FINF);
        #pragma unroll
        for (int e = 0; e < 9; ++e){
            float4 v = *(const float4*)&H[(size_t)(base + nbr[e])*384 + part*12 + q*4];
            mv.x = fmaxf(mv.x, v.x); mv.y = fmaxf(mv.y, v.y);
            mv.z = fmaxf(mv.z, v.z); mv.w = fmaxf(mv.w, v.w);
        }
        float4 xi = *(const float4*)&pi[q*4];
        *(float4*)&po[q*4] = make_float4(mv.x - xi.x, mv.y - xi.y, mv.z - xi.z, mv.w - xi.w);
    }
}

extern "C" void kernel_launch(void* const* d_in, const int* in_sizes, int n_in,
                              void* d_out, int out_size, void* d_ws, size_t ws_size,
                              hipStream_t stream)
{
    const float* x  = (const float*)d_in[0];
    const float* W1 = (const float*)d_in[1];
    const float* b1 = (const float*)d_in[2];
    const float* s1 = (const float*)d_in[3];
    const float* W2 = (const float*)d_in[4];
    const float* b2 = (const float*)d_in[5];
    const float* s2 = (const float*)d_in[6];
    const float* Wg = (const float*)d_in[7];
    const float* bg = (const float*)d_in[8];
    const float* sg = (const float*)d_in[9];
    const float* W3 = (const float*)d_in[10];
    const float* b3 = (const float*)d_in[11];
    const float* s3 = (const float*)d_in[12];
    const float* W4 = (const float*)d_in[13];
    const float* b4 = (const float*)d_in[14];
    const float* s4 = (const float*)d_in[15];

    float* H  = (float*)d_ws;                         // [25088][384]
    float* T1 = H  + (size_t)25088*384;               // [25088][192]; LL1 out (dead before knn); LL3 out later
    float* X2 = T1 + (size_t)25088*192;               // [25088][192]; PI during knn/merge; graphconv out later
    unsigned short* Xh = (unsigned short*)(X2 + (size_t)25088*192);  // [8][3200][192] fp16 hi
    unsigned short* Xl = Xh + (size_t)NB*NPAD*192;                   // fp16 lo
    unsigned* S2p = (unsigned*)(Xl + (size_t)NB*NPAD*192);           // [8][3200] packed -sq/2
    float* SQf = (float*)(S2p + (size_t)NB*NPAD);                    // [8][3136] fp32 sq
    int*   PI  = (int*)X2;                            // 1600*128*12 ints = 9.8 MB
    float* out = (float*)d_out;

    // ffn_lorentz #1
    ll_kernel<192, true , false, false, false><<<GRID_LL, 256, 0, stream>>>(x, 0,   W1, b1, s1, nullptr, nullptr, 0, T1, 192);
    ll_kernel<192, false, true , false, false><<<GRID_LL, 256, 0, stream>>>(T1, 192, W2, b2, s2, x,      nullptr, 0, H, 384);
    // graph conv
    conv_kernel<<<NB*NPAD/64, 256, 0, stream>>>(H, Xh, Xl, S2p, SQf);
    knn_kernel<<<GRID_KNN, 256, 0, stream>>>(Xh, Xl, S2p, PI);
    merge_msg_kernel<<<GRID_MSG, 256, 0, stream>>>(H, SQf, PI, H);
    ll_kernel<384, false, false, false, false><<<GRID_LL, 256, 0, stream>>>(H, 384,  Wg, bg, sg, nullptr, nullptr, 0, X2, 192);
    // ffn_lorentz #2 + final shortcut, transposed store
    ll_kernel<192, false, false, false, false><<<GRID_LL, 256, 0, stream>>>(X2, 192, W3, b3, s3, nullptr, nullptr, 0, T1, 192);
    ll_kernel<192, false, true , true , true ><<<GRID_LL, 256, 0, stream>>>(T1, 192, W4, b4, s4, x,      X2, 192, out, 0);
}

// Round 10
// 919.956 us; speedup vs baseline: 1.7039x; 1.2981x over previous
//
#include <hip/hip_runtime.h>
#include <math.h>

#define NB   8
#define NC   192
#define NPIX 3136
#define NPAD 3200
#define GRID_LL (NB*98)    // 784: M-tile 32
#define NIT  25            // i-tiles of 128 over padded 3200
#define NSP  8
#define GRID_KNN (NB*NIT*NSP)   // 1600
#define GRID_MSG (NB*196)  // 1568: 16 rows per block
#define FINF 3.4e38f

typedef _Float16 f16x8 __attribute__((ext_vector_type(8)));
typedef float   f32x16 __attribute__((ext_vector_type(16)));

__device__ __forceinline__ float gelu_f(float x){
    float u = 0.7978845608028654f * (x + 0.044715f * x * x * x);
    return 0.5f * x * (1.0f + tanhf(u));
}

// ---------------- min-lex top9 (exact rescore) ----------------
#define LESS9(da,ia,db,ib) ((da) < (db) || ((da) == (db) && (ia) < (ib)))
#define CSW9(a,ia,b,ib) { bool sw_ = LESS9(b,ib,a,ia); float tf_=(a); int ti_=(ia); \
    (a) = sw_? (b) : (a); (ia) = sw_? (ib) : (ia); (b) = sw_? tf_ : (b); (ib) = sw_? ti_ : (ib); }

struct Top9 {
    float d0,d1,d2,d3,d4,d5,d6,d7,d8;
    int   j0,j1,j2,j3,j4,j5,j6,j7,j8;
    __device__ __forceinline__ void init(){
        d0=d1=d2=d3=d4=d5=d6=d7=d8=FINF;
        j0=j1=j2=j3=j4=j5=j6=j7=j8=0x7FFFFFFF;
    }
    __device__ __forceinline__ void insert(float nd, int ni){
        if (!LESS9(nd, ni, d8, j8)) return;
        d8 = nd; j8 = ni;
        CSW9(d7,j7,d8,j8); CSW9(d6,j6,d7,j7); CSW9(d5,j5,d6,j6); CSW9(d4,j4,d5,j5);
        CSW9(d3,j3,d4,j4); CSW9(d2,j2,d3,j3); CSW9(d1,j1,d2,j2); CSW9(d0,j0,d1,j1);
    }
};

// ---------------- max-e top12 (knn screen, named locals) ----------------
#define RANKB(ea,ja,eb,jb) ((ea) > (eb) || ((ea) == (eb) && (ja) < (jb)))
#define CSWM(a,ja,b,jb) { bool s_ = RANKB(b,jb,a,ja); float tf_=(a); int ti_=(ja); \
    (a) = s_? (b) : (a); (ja) = s_? (jb) : (ja); (b) = s_? tf_ : (b); (jb) = s_? ti_ : (jb); }
#define INSMAX(e_,j_) \
    if (RANKB(e_,j_,t_e11,t_n11)) { t_e11=(e_); t_n11=(j_); \
        CSWM(t_e10,t_n10,t_e11,t_n11); CSWM(t_e9,t_n9,t_e10,t_n10); CSWM(t_e8,t_n8,t_e9,t_n9); \
        CSWM(t_e7,t_n7,t_e8,t_n8); CSWM(t_e6,t_n6,t_e7,t_n7); CSWM(t_e5,t_n5,t_e6,t_n6); \
        CSWM(t_e4,t_n4,t_e5,t_n5); CSWM(t_e3,t_n3,t_e4,t_n4); CSWM(t_e2,t_n2,t_e3,t_n3); \
        CSWM(t_e1,t_n1,t_e2,t_n2); CSWM(t_e0,t_n0,t_e1,t_n1); }

#define IE(A,R) { float e_=A[R]; int j_= jb_ + (((R)&3) + 8*((R)>>2)); INSMAX(e_,j_); }
#define IEQ(A,Q,QM) { if ((QM) >= t_e11){ IE(A,4*(Q)+0) IE(A,4*(Q)+1) IE(A,4*(Q)+2) IE(A,4*(Q)+3) } }
#define INSACC(A,JS) { \
    float qm0_ = fmaxf(fmaxf(A[0],A[1]),fmaxf(A[2],A[3])); \
    float qm1_ = fmaxf(fmaxf(A[4],A[5]),fmaxf(A[6],A[7])); \
    float qm2_ = fmaxf(fmaxf(A[8],A[9]),fmaxf(A[10],A[11])); \
    float qm3_ = fmaxf(fmaxf(A[12],A[13]),fmaxf(A[14],A[15])); \
    float am_ = fmaxf(fmaxf(qm0_,qm1_),fmaxf(qm2_,qm3_)); \
    if (am_ >= t_e11){ int jb_ = jg + (JS)*32 + 4*h; \
        IEQ(A,0,qm0_) IEQ(A,1,qm1_) IEQ(A,2,qm2_) IEQ(A,3,qm3_) } }

#define MF(ACC,AO,BO) ACC = __builtin_amdgcn_mfma_f32_32x32x16_f16(AO,BO,ACC,0,0,0);
#define ZERO16 {0,0,0,0,0,0,0,0,0,0,0,0,0,0,0,0}

// ---------------------------------------------------------------------------
// Fused GEMM + lorentz_linear (unchanged).
// ---------------------------------------------------------------------------
template<int K, bool IN_X, bool ADD_X, bool ADD_RM, bool OUT_T>
__global__ __launch_bounds__(256, 4) void ll_kernel(
    const float* __restrict__ Ain, int in_stride,
    const float* __restrict__ Wt, const float* __restrict__ bias,
    const float* __restrict__ sptr, const float* __restrict__ Xres,
    const float* __restrict__ Rrm, int r_stride,
    float* __restrict__ Out, int out_stride)
{
    __shared__ float lA[32*36];
    __shared__ float lW[32*196];

    const int tid = threadIdx.x;
    const int tx = tid & 15, ty = tid >> 4;
    const int bid = blockIdx.x;
    const int b  = bid / 98;
    const int n0 = (bid % 98) * 32;
    const int row0 = b * NPIX + n0;

    float acc[2][12];
    #pragma unroll
    for (int mi = 0; mi < 2; ++mi)
        #pragma unroll
        for (int j = 0; j < 12; ++j) acc[mi][j] = 0.f;

    for (int kt = 0; kt < K/32; ++kt){
        if (IN_X){
            int kk = tid >> 3;
            int m4 = (tid & 7) * 4;
            float4 v = *(const float4*)&Ain[(size_t)(b*NC + kt*32 + kk)*NPIX + n0 + m4];
            v.x = gelu_f(v.x); v.y = gelu_f(v.y); v.z = gelu_f(v.z); v.w = gelu_f(v.w);
            *(float4*)&lA[kk*36 + m4] = v;
        } else {
            int mm = tid >> 3;
            int k4 = (tid & 7) * 4;
            float4 v = *(const float4*)&Ain[(size_t)(row0 + mm)*in_stride + kt*32 + k4];
            v.x = gelu_f(v.x); v.y = gelu_f(v.y); v.z = gelu_f(v.z); v.w = gelu_f(v.w);
            lA[(k4+0)*36 + mm] = v.x; lA[(k4+1)*36 + mm] = v.y;
            lA[(k4+2)*36 + mm] = v.z; lA[(k4+3)*36 + mm] = v.w;
        }
        #pragma unroll
        for (int r = 0; r < 6; ++r){
            int e  = tid + r*256;
            int nn = e >> 3;
            int k4 = (e & 7) * 4;
            float4 v = *(const float4*)&Wt[nn*K + kt*32 + k4];
            lW[(k4+0)*196 + nn] = v.x; lW[(k4+1)*196 + nn] = v.y;
            lW[(k4+2)*196 + nn] = v.z; lW[(k4+3)*196 + nn] = v.w;
        }
        __syncthreads();
        #pragma unroll
        for (int kk = 0; kk < 32; ++kk){
            float2 a2 = *(const float2*)&lA[kk*36 + ty*2];
            float4 w0 = *(const float4*)&lW[kk*196 + tx*12];
            float4 w1 = *(const float4*)&lW[kk*196 + tx*12 + 4];
            float4 w2 = *(const float4*)&lW[kk*196 + tx*12 + 8];
            float aw[2]  = {a2.x, a2.y};
            float wv[12] = {w0.x,w0.y,w0.z,w0.w, w1.x,w1.y,w1.z,w1.w, w2.x,w2.y,w2.z,w2.w};
            #pragma unroll
            for (int mi = 0; mi < 2; ++mi)
                #pragma unroll
                for (int j = 0; j < 12; ++j)
                    acc[mi][j] = fmaf(aw[mi], wv[j], acc[mi][j]);
        }
        __syncthreads();
    }

    const int lane = tid & 63;
    float es = expf(sptr[0]);
    float bv[12];
    #pragma unroll
    for (int q = 0; q < 3; ++q){
        float4 t4 = *(const float4*)&bias[tx*12 + q*4];
        bv[q*4+0] = t4.x; bv[q*4+1] = t4.y; bv[q*4+2] = t4.z; bv[q*4+3] = t4.w;
    }
    #pragma unroll
    for (int mi = 0; mi < 2; ++mi){
        float part = 0.f;
        #pragma unroll
        for (int j = 0; j < 12; ++j){
            float y = acc[mi][j] + bv[j];
            acc[mi][j] = y;
            if (!(tx == 0 && j == 0)) part += y * y;
        }
        #pragma unroll
        for (int m = 1; m < 16; m <<= 1) part += __shfl_xor(part, m, 64);
        float y0   = __shfl(acc[mi][0], lane & 48, 64);
        float tval = es / (1.f + expf(-y0)) + 1.1f;
        float denom = fmaxf(part, 1e-8f);
        float sca  = (tval*tval - 1.f) / denom;
        float sqs  = sqrtf(sca);
        #pragma unroll
        for (int j = 0; j < 12; ++j){
            float o = acc[mi][j] * sqs;
            if (tx == 0 && j == 0) o = tval;
            acc[mi][j] = o;
        }
    }
    if (ADD_X){
        #pragma unroll
        for (int j = 0; j < 12; ++j){
            int c = tx*12 + j;
            float2 xv = *(const float2*)&Xres[(size_t)(b*NC + c)*NPIX + n0 + ty*2];
            acc[0][j] += xv.x; acc[1][j] += xv.y;
        }
    }
    if (ADD_RM){
        #pragma unroll
        for (int mi = 0; mi < 2; ++mi){
            #pragma unroll
            for (int q = 0; q < 3; ++q){
                float4 rv = *(const float4*)&Rrm[(size_t)(row0 + ty*2 + mi)*r_stride + tx*12 + q*4];
                acc[mi][q*4+0] += rv.x; acc[mi][q*4+1] += rv.y;
                acc[mi][q*4+2] += rv.z; acc[mi][q*4+3] += rv.w;
            }
        }
    }
    if (OUT_T){
        #pragma unroll
        for (int j = 0; j < 12; ++j){
            int c = tx*12 + j;
            *(float2*)&Out[(size_t)(b*NC + c)*NPIX + n0 + ty*2] = make_float2(acc[0][j], acc[1][j]);
        }
    } else {
        #pragma unroll
        for (int mi = 0; mi < 2; ++mi){
            #pragma unroll
            for (int q = 0; q < 3; ++q){
                float4 o = make_float4(acc[mi][q*4+0], acc[mi][q*4+1], acc[mi][q*4+2], acc[mi][q*4+3]);
                *(float4*)&Out[(size_t)(row0 + ty*2 + mi)*out_stride + tx*12 + q*4] = o;
            }
        }
    }
}

// ---------------------------------------------------------------------------
// conv: H fp32 rows -> Xh/Xl fp16 hi/lo [8][3200][192], S2 packed(-sq/2 hi,lo),
// SQf fp32 row sq-norms. Pad rows: x=0, s2=-30000.
// ---------------------------------------------------------------------------
__device__ __forceinline__ unsigned pack2(float a, float b, unsigned &lo){
    union { _Float16 f; unsigned short u; } ha, hb, la, lb;
    ha.f = (_Float16)a; hb.f = (_Float16)b;
    float ra = a - (float)ha.f, rb = b - (float)hb.f;
    la.f = (_Float16)ra; lb.f = (_Float16)rb;
    lo = (unsigned)la.u | ((unsigned)lb.u << 16);
    return (unsigned)ha.u | ((unsigned)hb.u << 16);
}

__global__ __launch_bounds__(256) void conv_kernel(
    const float* __restrict__ H, unsigned short* __restrict__ Xh,
    unsigned short* __restrict__ Xl, unsigned* __restrict__ S2,
    float* __restrict__ SQf)
{
    const int tid = threadIdx.x;
    const int r = blockIdx.x*64 + (tid >> 2);
    const int b = r / NPAD, rl = r - b*NPAD;
    const int part = tid & 3;
    const size_t ob = ((size_t)b*NPAD + rl)*192 + part*48;

    if (rl < NPIX){
        const float* src = H + ((size_t)b*NPIX + rl)*384 + part*48;
        float s = 0.f;
        #pragma unroll
        for (int q = 0; q < 6; ++q){
            float4 v0 = *(const float4*)&src[q*8];
            float4 v1 = *(const float4*)&src[q*8 + 4];
            s = fmaf(v0.x,v0.x, fmaf(v0.y,v0.y, fmaf(v0.z,v0.z, fmaf(v0.w,v0.w, s))));
            s = fmaf(v1.x,v1.x, fmaf(v1.y,v1.y, fmaf(v1.z,v1.z, fmaf(v1.w,v1.w, s))));
            uint4 hv, lv;
            hv.x = pack2(v0.x, v0.y, lv.x);
            hv.y = pack2(v0.z, v0.w, lv.y);
            hv.z = pack2(v1.x, v1.y, lv.z);
            hv.w = pack2(v1.z, v1.w, lv.w);
            *(uint4*)&Xh[ob + q*8] = hv;
            *(uint4*)&Xl[ob + q*8] = lv;
        }
        s += __shfl_xor(s, 1, 64);
        s += __shfl_xor(s, 2, 64);
        if (part == 0){
            SQf[(size_t)b*NPIX + rl] = s;
            float s2 = -0.5f * s;
            union { _Float16 f; unsigned short u; } hh, ll;
            hh.f = (_Float16)s2;
            float rr = s2 - (float)hh.f;
            ll.f = (_Float16)rr;
            S2[(size_t)b*NPAD + rl] = (unsigned)hh.u | ((unsigned)ll.u << 16);
        }
    } else {
        uint4 z = make_uint4(0,0,0,0);
        #pragma unroll
        for (int q = 0; q < 6; ++q){
            *(uint4*)&Xh[ob + q*8] = z;
            *(uint4*)&Xl[ob + q*8] = z;
        }
        if (part == 0){
            union { _Float16 f; unsigned short u; } p;
            p.f = (_Float16)(-30000.0f);
            S2[(size_t)b*NPAD + rl] = (unsigned)p.u;
        }
    }
}

// ---------------------------------------------------------------------------
// MFMA kNN screen. Stride-5 uint4 LDS rows (conflict-minimal, no swizzle math).
// 4 waves, i-tile 128 (wave w: i-cols i0+w*32..+31); 3-pass fp16 hi/lo;
// e = dot - sq_j/2 via augmented channel. Lane owns i-col lane&31; top-12
// max-e in named registers with acc/quad-level max gating; writes (e, idx).
// ---------------------------------------------------------------------------
__global__ __launch_bounds__(256) __attribute__((amdgpu_waves_per_eu(2))) void knn_kernel(
    const unsigned short* __restrict__ Xh, const unsigned short* __restrict__ Xl,
    const unsigned* __restrict__ S2, float* __restrict__ PD, int* __restrict__ PI)
{
    __shared__ uint4 lds[2560];   // 4 arrays (Ah,Al,Bh,Bl) x 128 rows x stride-5

    const int tid  = threadIdx.x;
    const int lane = tid & 63;
    const int w    = tid >> 6;
    const int l31  = lane & 31;
    const int h    = lane >> 5;
    const int bid  = blockIdx.x;
    const int b    = bid & 7;
    const int t2   = bid >> 3;
    const int itile = t2 >> 3;
    const int sp    = t2 & 7;
    const int i0    = itile * 128;
    const int g0 = (sp*25)/8, g1 = ((sp+1)*25)/8;
    const size_t rowb = (size_t)b * NPAD;

    float t_e0=-FINF,t_e1=-FINF,t_e2=-FINF,t_e3=-FINF,t_e4=-FINF,t_e5=-FINF,
          t_e6=-FINF,t_e7=-FINF,t_e8=-FINF,t_e9=-FINF,t_e10=-FINF,t_e11=-FINF;
    int   t_n0=0x7FFFFFFF,t_n1=0x7FFFFFFF,t_n2=0x7FFFFFFF,t_n3=0x7FFFFFFF,
          t_n4=0x7FFFFFFF,t_n5=0x7FFFFFFF,t_n6=0x7FFFFFFF,t_n7=0x7FFFFFFF,
          t_n8=0x7FFFFFFF,t_n9=0x7FFFFFFF,t_n10=0x7FFFFFFF,t_n11=0x7FFFFFFF;

    for (int g = g0; g < g1; ++g){
        const int jg = g*128;
        f32x16 acc0 = ZERO16, acc1 = ZERO16, acc2 = ZERO16, acc3 = ZERO16;

        for (int kc = 0; kc < 6; ++kc){
            __syncthreads();
            #pragma unroll
            for (int rr = 0; rr < 8; ++rr){
                int u   = tid + rr*256;
                int arr = u >> 9;
                int rs  = (u >> 2) & 127;
                int seg = u & 3;
                int row = (arr < 2) ? (jg + rs) : (i0 + rs);
                const unsigned short* sptr = (arr & 1) ? Xl : Xh;
                uint4 v = *(const uint4*)&sptr[(rowb + row)*192 + kc*32 + seg*8];
                lds[arr*640 + rs*5 + seg] = v;
            }
            __syncthreads();
            #pragma unroll
            for (int ks = 0; ks < 2; ++ks){
                int kq  = ks*2 + h;
                int rb  = l31*5 + kq;
                f16x8 bh = __builtin_bit_cast(f16x8, lds[1280 + w*160 + rb]);
                f16x8 bl = __builtin_bit_cast(f16x8, lds[1920 + w*160 + rb]);
                f16x8 a0h = __builtin_bit_cast(f16x8, lds[      0 + rb]);
                f16x8 a0l = __builtin_bit_cast(f16x8, lds[640 +   0 + rb]);
                MF(acc0, a0h, bh) MF(acc0, a0l, bh) MF(acc0, a0h, bl)
                f16x8 a1h = __builtin_bit_cast(f16x8, lds[      160 + rb]);
                f16x8 a1l = __builtin_bit_cast(f16x8, lds[640 + 160 + rb]);
                MF(acc1, a1h, bh) MF(acc1, a1l, bh) MF(acc1, a1h, bl)
                f16x8 a2h = __builtin_bit_cast(f16x8, lds[      320 + rb]);
                f16x8 a2l = __builtin_bit_cast(f16x8, lds[640 + 320 + rb]);
                MF(acc2, a2h, bh) MF(acc2, a2l, bh) MF(acc2, a2h, bl)
                f16x8 a3h = __builtin_bit_cast(f16x8, lds[      480 + rb]);
                f16x8 a3l = __builtin_bit_cast(f16x8, lds[640 + 480 + rb]);
                MF(acc3, a3h, bh) MF(acc3, a3l, bh) MF(acc3, a3h, bl)
            }
        }

        // k=192 channel: A = -sq_j/2 (hi/lo), B = 1 at k-elem 0 (h==0 lanes)
        {
            unsigned m  = (h == 0) ? 0xFFFFFFFFu : 0u;
            unsigned om = 0x3C00u & m;
            f16x8 one = __builtin_bit_cast(f16x8, make_uint4(om, 0, 0, 0));
            unsigned s0 = S2[rowb + jg +  0 + l31];
            unsigned s1 = S2[rowb + jg + 32 + l31];
            unsigned s2 = S2[rowb + jg + 64 + l31];
            unsigned s3 = S2[rowb + jg + 96 + l31];
            f16x8 a;
            a = __builtin_bit_cast(f16x8, make_uint4((s0 & 0xFFFFu) & m, 0,0,0)); MF(acc0, a, one)
            a = __builtin_bit_cast(f16x8, make_uint4((s0 >> 16)     & m, 0,0,0)); MF(acc0, a, one)
            a = __builtin_bit_cast(f16x8, make_uint4((s1 & 0xFFFFu) & m, 0,0,0)); MF(acc1, a, one)
            a = __builtin_bit_cast(f16x8, make_uint4((s1 >> 16)     & m, 0,0,0)); MF(acc1, a, one)
            a = __builtin_bit_cast(f16x8, make_uint4((s2 & 0xFFFFu) & m, 0,0,0)); MF(acc2, a, one)
            a = __builtin_bit_cast(f16x8, make_uint4((s2 >> 16)     & m, 0,0,0)); MF(acc2, a, one)
            a = __builtin_bit_cast(f16x8, make_uint4((s3 & 0xFFFFu) & m, 0,0,0)); MF(acc3, a, one)
            a = __builtin_bit_cast(f16x8, make_uint4((s3 >> 16)     & m, 0,0,0)); MF(acc3, a, one)
        }

        INSACC(acc0, 0)
        INSACC(acc1, 1)
        INSACC(acc2, 2)
        INSACC(acc3, 3)
    }

    // merge lane pair (same i-col, disjoint j rows)
    #define MRG(E,N) { float oe_ = __shfl(E, lane ^ 32, 64); int on_ = __shfl(N, lane ^ 32, 64); \
                       if (lane < 32) { INSMAX(oe_, on_) } }
    MRG(t_e0,t_n0) MRG(t_e1,t_n1) MRG(t_e2,t_n2) MRG(t_e3,t_n3) MRG(t_e4,t_n4) MRG(t_e5,t_n5)
    MRG(t_e6,t_n6) MRG(t_e7,t_n7) MRG(t_e8,t_n8) MRG(t_e9,t_n9) MRG(t_e10,t_n10) MRG(t_e11,t_n11)

    if (lane < 32){
        size_t po = ((size_t)(t2*8 + b)*128 + (size_t)w*32 + l31)*12;
        PD[po+ 0] = t_e0;  PD[po+ 1] = t_e1;  PD[po+ 2] = t_e2;  PD[po+ 3] = t_e3;
        PD[po+ 4] = t_e4;  PD[po+ 5] = t_e5;  PD[po+ 6] = t_e6;  PD[po+ 7] = t_e7;
        PD[po+ 8] = t_e8;  PD[po+ 9] = t_e9;  PD[po+10] = t_e10; PD[po+11] = t_e11;
        PI[po+ 0] = t_n0;  PI[po+ 1] = t_n1;  PI[po+ 2] = t_n2;  PI[po+ 3] = t_n3;
        PI[po+ 4] = t_n4;  PI[po+ 5] = t_n5;  PI[po+ 6] = t_n6;  PI[po+ 7] = t_n7;
        PI[po+ 8] = t_n8;  PI[po+ 9] = t_n9;  PI[po+10] = t_n10; PI[po+11] = t_n11;
    }
}

// ---------------------------------------------------------------------------
// 8-way sorted-list merge -> global approx top-12 -> exact fp32 rescore of 12
// -> top-9 -> max-message. 16 rows/block.
// ---------------------------------------------------------------------------
__global__ __launch_bounds__(256) void merge_msg_kernel(
    const float* __restrict__ H, const float* __restrict__ SQf,
    const float* __restrict__ PD, const int* __restrict__ PI,
    float* __restrict__ Hout)
{
    __shared__ float liX[16*196];
    __shared__ float ev[1600];     // [16 rows][stride 100]: 8 lists x 12
    __shared__ int   jv[1600];
    __shared__ float cd[192];
    __shared__ int   cidx[192];
    __shared__ int   fidx[144];

    const int tid = threadIdx.x;
    const int bid = blockIdx.x;
    const int b  = bid / 196;
    const int i0 = (bid % 196) * 16;
    const int base = b * NPIX;

    // stage the 16 i-rows (first 192 cols of H)
    #pragma unroll
    for (int k = 0; k < 3; ++k){
        int f = tid + k*256;
        int r = f / 48, c4 = f % 48;
        *(float4*)&liX[r*196 + c4*4] = *(const float4*)&H[(size_t)(base + i0 + r)*384 + c4*4];
    }
    // stage candidate lists
    if (tid < 128){
        int r = tid >> 3, sp = tid & 7;
        int i = i0 + r;
        size_t po = ((size_t)(((i>>7)*8 + sp)*8 + b)*128 + (i & 127))*12;
        #pragma unroll
        for (int q = 0; q < 3; ++q){
            *(float4*)&ev[r*100 + sp*12 + q*4] = *(const float4*)&PD[po + q*4];
            *(int4*)  &jv[r*100 + sp*12 + q*4] = *(const int4*)  &PI[po + q*4];
        }
    }
    __syncthreads();

    // per-row 8-way merge (lists sorted by e desc, j asc) -> top-12 indices
    if (tid < 16){
        int r = tid;
        int h0=0,h1=0,h2=0,h3=0,h4=0,h5=0,h6=0,h7=0;
        #pragma unroll
        for (int p = 0; p < 12; ++p){
            float be = -FINF; int bj = 0x7FFFFFFF; int bs = 0;
#define HEADC(SP,HV) { \
            float e_ = (HV < 12) ? ev[r*100 + SP*12 + HV] : -FINF; \
            int   j_ = (HV < 12) ? jv[r*100 + SP*12 + HV] : 0x7FFFFFFF; \
            bool bt_ = (e_ > be) || (e_ == be && j_ < bj); \
            be = bt_? e_ : be; bj = bt_? j_ : bj; bs = bt_? SP : bs; }
            HEADC(0,h0) HEADC(1,h1) HEADC(2,h2) HEADC(3,h3)
            HEADC(4,h4) HEADC(5,h5) HEADC(6,h6) HEADC(7,h7)
#undef HEADC
            cidx[r*12 + p] = bj;
            h0 += (bs==0); h1 += (bs==1); h2 += (bs==2); h3 += (bs==3);
            h4 += (bs==4); h5 += (bs==5); h6 += (bs==6); h7 += (bs==7);
        }
    }
    __syncthreads();

    // exact fp32 rescore of the 12 candidates per row
    if (tid < 192){
        int r = tid / 12, p = tid - r*12;
        int j = cidx[r*12 + p];
        const float* hj = &H[(size_t)(base + j)*384];
        float dot = 0.f;
        #pragma unroll
        for (int q = 0; q < 48; ++q){
            float4 xv = *(const float4*)&liX[r*196 + q*4];
            float4 yv = *(const float4*)&hj[q*4];
            dot = fmaf(xv.x,yv.x, fmaf(xv.y,yv.y, fmaf(xv.z,yv.z, fmaf(xv.w,yv.w, dot))));
        }
        cd[r*12 + p] = SQf[base + j] - 2.f*dot;
    }
    __syncthreads();

    if (tid < 16){
        int r = tid;
        Top9 m; m.init();
        #pragma unroll
        for (int c = 0; c < 12; ++c) m.insert(cd[r*12 + c], cidx[r*12 + c]);
        fidx[r*9+0]=m.j0; fidx[r*9+1]=m.j1; fidx[r*9+2]=m.j2; fidx[r*9+3]=m.j3;
        fidx[r*9+4]=m.j4; fidx[r*9+5]=m.j5; fidx[r*9+6]=m.j6; fidx[r*9+7]=m.j7;
        fidx[r*9+8]=m.j8;
    }
    __syncthreads();

    int rr = tid >> 4, part = tid & 15;
    int ii = i0 + rr;
    int nbr[9];
    #pragma unroll
    for (int e = 0; e < 9; ++e) nbr[e] = fidx[rr*9 + e];
    const float* pi = H + (size_t)(base + ii)*384 + part*12;
    float* po = Hout + (size_t)(base + ii)*384 + 192 + part*12;
    #pragma unroll
    for (int q = 0; q < 3; ++q){
        float4 mv = make_float4(-FINF, -FINF, -FINF, -FINF);
        #pragma unroll
        for (int e = 0; e < 9; ++e){
            float4 v = *(const float4*)&H[(size_t)(base + nbr[e])*384 + part*12 + q*4];
            mv.x = fmaxf(mv.x, v.x); mv.y = fmaxf(mv.y, v.y);
            mv.z = fmaxf(mv.z, v.z); mv.w = fmaxf(mv.w, v.w);
        }
        float4 xi = *(const float4*)&pi[q*4];
        *(float4*)&po[q*4] = make_float4(mv.x - xi.x, mv.y - xi.y, mv.z - xi.z, mv.w - xi.w);
    }
}

extern "C" void kernel_launch(void* const* d_in, const int* in_sizes, int n_in,
                              void* d_out, int out_size, void* d_ws, size_t ws_size,
                              hipStream_t stream)
{
    const float* x  = (const float*)d_in[0];
    const float* W1 = (const float*)d_in[1];
    const float* b1 = (const float*)d_in[2];
    const float* s1 = (const float*)d_in[3];
    const float* W2 = (const float*)d_in[4];
    const float* b2 = (const float*)d_in[5];
    const float* s2 = (const float*)d_in[6];
    const float* Wg = (const float*)d_in[7];
    const float* bg = (const float*)d_in[8];
    const float* sg = (const float*)d_in[9];
    const float* W3 = (const float*)d_in[10];
    const float* b3 = (const float*)d_in[11];
    const float* s3 = (const float*)d_in[12];
    const float* W4 = (const float*)d_in[13];
    const float* b4 = (const float*)d_in[14];
    const float* s4 = (const float*)d_in[15];

    float* H  = (float*)d_ws;                         // [25088][384]
    float* T1 = H  + (size_t)25088*384;               // LL1 out; PI during knn/merge; LL3 out later
    float* X2 = T1 + (size_t)25088*192;               // PD during knn/merge; graph-conv out later
    unsigned short* Xh = (unsigned short*)(X2 + (size_t)25088*192);  // [8][3200][192] fp16 hi
    unsigned short* Xl = Xh + (size_t)NB*NPAD*192;                   // fp16 lo
    unsigned* S2p = (unsigned*)(Xl + (size_t)NB*NPAD*192);           // [8][3200] packed -sq/2
    float* SQf = (float*)(S2p + (size_t)NB*NPAD);                    // [8][3136] fp32 sq
    float* PD  = X2;                                  // 1600*128*12 floats = 9.8 MB
    int*   PI  = (int*)T1;                            // 1600*128*12 ints  = 9.8 MB
    float* out = (float*)d_out;

    // ffn_lorentz #1 (LL1 -> T1 is consumed by LL2 before PI reuses T1)
    ll_kernel<192, true , false, false, false><<<GRID_LL, 256, 0, stream>>>(x, 0,   W1, b1, s1, nullptr, nullptr, 0, T1, 192);
    ll_kernel<192, false, true , false, false><<<GRID_LL, 256, 0, stream>>>(T1, 192, W2, b2, s2, x,      nullptr, 0, H, 384);
    // graph conv
    conv_kernel<<<NB*NPAD/64, 256, 0, stream>>>(H, Xh, Xl, S2p, SQf);
    knn_kernel<<<GRID_KNN, 256, 0, stream>>>(Xh, Xl, S2p, PD, PI);
    merge_msg_kernel<<<GRID_MSG, 256, 0, stream>>>(H, SQf, PD, PI, H);
    ll_kernel<384, false, false, false, false><<<GRID_LL, 256, 0, stream>>>(H, 384,  Wg, bg, sg, nullptr, nullptr, 0, X2, 192);
    // ffn_lorentz #2 + final shortcut, transposed store
    ll_kernel<192, false, false, false, false><<<GRID_LL, 256, 0, stream>>>(X2, 192, W3, b3, s3, nullptr, nullptr, 0, T1, 192);
    ll_kernel<192, false, true , true , true ><<<GRID_LL, 256, 0, stream>>>(T1, 192, W4, b4, s4, x,      X2, 192, out, 0);
}

// Round 11
// 645.489 us; speedup vs baseline: 2.4284x; 1.4252x over previous
//
#include <hip/hip_runtime.h>
#include <math.h>

#define NB   8
#define NC   192
#define NPIX 3136
#define NPAD 3200
#define GRID_LL (NB*98)    // 784: M-tile 32
#define NIT  25            // i-tiles of 128 over padded 3200
#define NSP  8
#define GRID_KNN (NB*NIT*NSP)   // 1600
#define GRID_MSG (NB*196)  // 1568: 16 rows per block
#define FINF 3.4e38f

typedef _Float16 f16x8 __attribute__((ext_vector_type(8)));
typedef float   f32x16 __attribute__((ext_vector_type(16)));

__device__ __forceinline__ float gelu_f(float x){
    float u = 0.7978845608028654f * (x + 0.044715f * x * x * x);
    return 0.5f * x * (1.0f + tanhf(u));
}

// ---------------- min-lex top9 (exact rescore) ----------------
#define LESS9(da,ia,db,ib) ((da) < (db) || ((da) == (db) && (ia) < (ib)))
#define CSW9(a,ia,b,ib) { bool sw_ = LESS9(b,ib,a,ia); float tf_=(a); int ti_=(ia); \
    (a) = sw_? (b) : (a); (ia) = sw_? (ib) : (ia); (b) = sw_? tf_ : (b); (ib) = sw_? ti_ : (ib); }

struct Top9 {
    float d0,d1,d2,d3,d4,d5,d6,d7,d8;
    int   j0,j1,j2,j3,j4,j5,j6,j7,j8;
    __device__ __forceinline__ void init(){
        d0=d1=d2=d3=d4=d5=d6=d7=d8=FINF;
        j0=j1=j2=j3=j4=j5=j6=j7=j8=0x7FFFFFFF;
    }
    __device__ __forceinline__ void insert(float nd, int ni){
        if (!LESS9(nd, ni, d8, j8)) return;
        d8 = nd; j8 = ni;
        CSW9(d7,j7,d8,j8); CSW9(d6,j6,d7,j7); CSW9(d5,j5,d6,j6); CSW9(d4,j4,d5,j5);
        CSW9(d3,j3,d4,j4); CSW9(d2,j2,d3,j3); CSW9(d1,j1,d2,j2); CSW9(d0,j0,d1,j1);
    }
};

// ---------------- u32-key top12 (knn screen) ----------------
// key = (monotone(e) & ~0xFFF) | (4095 - j): key desc == (e desc, j asc)
__device__ __forceinline__ unsigned f2mono(float e){
    unsigned u = __float_as_uint(e);
    return u ^ ((unsigned)((int)u >> 31) | 0x80000000u);
}

#define CSK(a,b) { unsigned h_ = (a) > (b) ? (a) : (b); unsigned l_ = (a) > (b) ? (b) : (a); (a) = h_; (b) = l_; }
#define INSKEY(x_) if ((x_) > t_k11){ t_k11 = (x_); \
    CSK(t_k10,t_k11) CSK(t_k9,t_k10) CSK(t_k8,t_k9) CSK(t_k7,t_k8) \
    CSK(t_k6,t_k7) CSK(t_k5,t_k6) CSK(t_k4,t_k5) CSK(t_k3,t_k4) \
    CSK(t_k2,t_k3) CSK(t_k1,t_k2) CSK(t_k0,t_k1) }

#define KQ(A,Q) { \
    unsigned q0_ = (f2mono(A[4*(Q)+0]) & 0xFFFFF000u) | (unsigned)(jinvb_ - 8*(Q)    ); \
    unsigned q1_ = (f2mono(A[4*(Q)+1]) & 0xFFFFF000u) | (unsigned)(jinvb_ - 8*(Q) - 1); \
    unsigned q2_ = (f2mono(A[4*(Q)+2]) & 0xFFFFF000u) | (unsigned)(jinvb_ - 8*(Q) - 2); \
    unsigned q3_ = (f2mono(A[4*(Q)+3]) & 0xFFFFF000u) | (unsigned)(jinvb_ - 8*(Q) - 3); \
    unsigned qa_ = q0_ > q1_ ? q0_ : q1_; \
    unsigned qb_ = q2_ > q3_ ? q2_ : q3_; \
    unsigned qm_ = qa_ > qb_ ? qa_ : qb_; \
    if (qm_ > t_k11){ INSKEY(q0_) INSKEY(q1_) INSKEY(q2_) INSKEY(q3_) } }

#define INSACCK(A,JS) { int jinvb_ = 4095 - (jg + (JS)*32 + 4*h); \
    KQ(A,0) KQ(A,1) KQ(A,2) KQ(A,3) }

#define MF(ACC,AO,BO) ACC = __builtin_amdgcn_mfma_f32_32x32x16_f16(AO,BO,ACC,0,0,0);
#define ZERO16 {0,0,0,0,0,0,0,0,0,0,0,0,0,0,0,0}

// ---------------------------------------------------------------------------
// Fused GEMM + lorentz_linear (unchanged).
// ---------------------------------------------------------------------------
template<int K, bool IN_X, bool ADD_X, bool ADD_RM, bool OUT_T>
__global__ __launch_bounds__(256, 4) void ll_kernel(
    const float* __restrict__ Ain, int in_stride,
    const float* __restrict__ Wt, const float* __restrict__ bias,
    const float* __restrict__ sptr, const float* __restrict__ Xres,
    const float* __restrict__ Rrm, int r_stride,
    float* __restrict__ Out, int out_stride)
{
    __shared__ float lA[32*36];
    __shared__ float lW[32*196];

    const int tid = threadIdx.x;
    const int tx = tid & 15, ty = tid >> 4;
    const int bid = blockIdx.x;
    const int b  = bid / 98;
    const int n0 = (bid % 98) * 32;
    const int row0 = b * NPIX + n0;

    float acc[2][12];
    #pragma unroll
    for (int mi = 0; mi < 2; ++mi)
        #pragma unroll
        for (int j = 0; j < 12; ++j) acc[mi][j] = 0.f;

    for (int kt = 0; kt < K/32; ++kt){
        if (IN_X){
            int kk = tid >> 3;
            int m4 = (tid & 7) * 4;
            float4 v = *(const float4*)&Ain[(size_t)(b*NC + kt*32 + kk)*NPIX + n0 + m4];
            v.x = gelu_f(v.x); v.y = gelu_f(v.y); v.z = gelu_f(v.z); v.w = gelu_f(v.w);
            *(float4*)&lA[kk*36 + m4] = v;
        } else {
            int mm = tid >> 3;
            int k4 = (tid & 7) * 4;
            float4 v = *(const float4*)&Ain[(size_t)(row0 + mm)*in_stride + kt*32 + k4];
            v.x = gelu_f(v.x); v.y = gelu_f(v.y); v.z = gelu_f(v.z); v.w = gelu_f(v.w);
            lA[(k4+0)*36 + mm] = v.x; lA[(k4+1)*36 + mm] = v.y;
            lA[(k4+2)*36 + mm] = v.z; lA[(k4+3)*36 + mm] = v.w;
        }
        #pragma unroll
        for (int r = 0; r < 6; ++r){
            int e  = tid + r*256;
            int nn = e >> 3;
            int k4 = (e & 7) * 4;
            float4 v = *(const float4*)&Wt[nn*K + kt*32 + k4];
            lW[(k4+0)*196 + nn] = v.x; lW[(k4+1)*196 + nn] = v.y;
            lW[(k4+2)*196 + nn] = v.z; lW[(k4+3)*196 + nn] = v.w;
        }
        __syncthreads();
        #pragma unroll
        for (int kk = 0; kk < 32; ++kk){
            float2 a2 = *(const float2*)&lA[kk*36 + ty*2];
            float4 w0 = *(const float4*)&lW[kk*196 + tx*12];
            float4 w1 = *(const float4*)&lW[kk*196 + tx*12 + 4];
            float4 w2 = *(const float4*)&lW[kk*196 + tx*12 + 8];
            float aw[2]  = {a2.x, a2.y};
            float wv[12] = {w0.x,w0.y,w0.z,w0.w, w1.x,w1.y,w1.z,w1.w, w2.x,w2.y,w2.z,w2.w};
            #pragma unroll
            for (int mi = 0; mi < 2; ++mi)
                #pragma unroll
                for (int j = 0; j < 12; ++j)
                    acc[mi][j] = fmaf(aw[mi], wv[j], acc[mi][j]);
        }
        __syncthreads();
    }

    const int lane = tid & 63;
    float es = expf(sptr[0]);
    float bv[12];
    #pragma unroll
    for (int q = 0; q < 3; ++q){
        float4 t4 = *(const float4*)&bias[tx*12 + q*4];
        bv[q*4+0] = t4.x; bv[q*4+1] = t4.y; bv[q*4+2] = t4.z; bv[q*4+3] = t4.w;
    }
    #pragma unroll
    for (int mi = 0; mi < 2; ++mi){
        float part = 0.f;
        #pragma unroll
        for (int j = 0; j < 12; ++j){
            float y = acc[mi][j] + bv[j];
            acc[mi][j] = y;
            if (!(tx == 0 && j == 0)) part += y * y;
        }
        #pragma unroll
        for (int m = 1; m < 16; m <<= 1) part += __shfl_xor(part, m, 64);
        float y0   = __shfl(acc[mi][0], lane & 48, 64);
        float tval = es / (1.f + expf(-y0)) + 1.1f;
        float denom = fmaxf(part, 1e-8f);
        float sca  = (tval*tval - 1.f) / denom;
        float sqs  = sqrtf(sca);
        #pragma unroll
        for (int j = 0; j < 12; ++j){
            float o = acc[mi][j] * sqs;
            if (tx == 0 && j == 0) o = tval;
            acc[mi][j] = o;
        }
    }
    if (ADD_X){
        #pragma unroll
        for (int j = 0; j < 12; ++j){
            int c = tx*12 + j;
            float2 xv = *(const float2*)&Xres[(size_t)(b*NC + c)*NPIX + n0 + ty*2];
            acc[0][j] += xv.x; acc[1][j] += xv.y;
        }
    }
    if (ADD_RM){
        #pragma unroll
        for (int mi = 0; mi < 2; ++mi){
            #pragma unroll
            for (int q = 0; q < 3; ++q){
                float4 rv = *(const float4*)&Rrm[(size_t)(row0 + ty*2 + mi)*r_stride + tx*12 + q*4];
                acc[mi][q*4+0] += rv.x; acc[mi][q*4+1] += rv.y;
                acc[mi][q*4+2] += rv.z; acc[mi][q*4+3] += rv.w;
            }
        }
    }
    if (OUT_T){
        #pragma unroll
        for (int j = 0; j < 12; ++j){
            int c = tx*12 + j;
            *(float2*)&Out[(size_t)(b*NC + c)*NPIX + n0 + ty*2] = make_float2(acc[0][j], acc[1][j]);
        }
    } else {
        #pragma unroll
        for (int mi = 0; mi < 2; ++mi){
            #pragma unroll
            for (int q = 0; q < 3; ++q){
                float4 o = make_float4(acc[mi][q*4+0], acc[mi][q*4+1], acc[mi][q*4+2], acc[mi][q*4+3]);
                *(float4*)&Out[(size_t)(row0 + ty*2 + mi)*out_stride + tx*12 + q*4] = o;
            }
        }
    }
}

// ---------------------------------------------------------------------------
// conv: H fp32 rows -> Xh/Xl fp16 hi/lo [8][3200][192], S2 packed(-sq/2 hi,lo),
// SQf fp32 row sq-norms. Pad rows: x=0, s2=-30000.
// ---------------------------------------------------------------------------
__device__ __forceinline__ unsigned pack2(float a, float b, unsigned &lo){
    union { _Float16 f; unsigned short u; } ha, hb, la, lb;
    ha.f = (_Float16)a; hb.f = (_Float16)b;
    float ra = a - (float)ha.f, rb = b - (float)hb.f;
    la.f = (_Float16)ra; lb.f = (_Float16)rb;
    lo = (unsigned)la.u | ((unsigned)lb.u << 16);
    return (unsigned)ha.u | ((unsigned)hb.u << 16);
}

__global__ __launch_bounds__(256) void conv_kernel(
    const float* __restrict__ H, unsigned short* __restrict__ Xh,
    unsigned short* __restrict__ Xl, unsigned* __restrict__ S2,
    float* __restrict__ SQf)
{
    const int tid = threadIdx.x;
    const int r = blockIdx.x*64 + (tid >> 2);
    const int b = r / NPAD, rl = r - b*NPAD;
    const int part = tid & 3;
    const size_t ob = ((size_t)b*NPAD + rl)*192 + part*48;

    if (rl < NPIX){
        const float* src = H + ((size_t)b*NPIX + rl)*384 + part*48;
        float s = 0.f;
        #pragma unroll
        for (int q = 0; q < 6; ++q){
            float4 v0 = *(const float4*)&src[q*8];
            float4 v1 = *(const float4*)&src[q*8 + 4];
            s = fmaf(v0.x,v0.x, fmaf(v0.y,v0.y, fmaf(v0.z,v0.z, fmaf(v0.w,v0.w, s))));
            s = fmaf(v1.x,v1.x, fmaf(v1.y,v1.y, fmaf(v1.z,v1.z, fmaf(v1.w,v1.w, s))));
            uint4 hv, lv;
            hv.x = pack2(v0.x, v0.y, lv.x);
            hv.y = pack2(v0.z, v0.w, lv.y);
            hv.z = pack2(v1.x, v1.y, lv.z);
            hv.w = pack2(v1.z, v1.w, lv.w);
            *(uint4*)&Xh[ob + q*8] = hv;
            *(uint4*)&Xl[ob + q*8] = lv;
        }
        s += __shfl_xor(s, 1, 64);
        s += __shfl_xor(s, 2, 64);
        if (part == 0){
            SQf[(size_t)b*NPIX + rl] = s;
            float s2 = -0.5f * s;
            union { _Float16 f; unsigned short u; } hh, ll;
            hh.f = (_Float16)s2;
            float rr = s2 - (float)hh.f;
            ll.f = (_Float16)rr;
            S2[(size_t)b*NPAD + rl] = (unsigned)hh.u | ((unsigned)ll.u << 16);
        }
    } else {
        uint4 z = make_uint4(0,0,0,0);
        #pragma unroll
        for (int q = 0; q < 6; ++q){
            *(uint4*)&Xh[ob + q*8] = z;
            *(uint4*)&Xl[ob + q*8] = z;
        }
        if (part == 0){
            union { _Float16 f; unsigned short u; } p;
            p.f = (_Float16)(-30000.0f);
            S2[(size_t)b*NPAD + rl] = (unsigned)p.u;
        }
    }
}

// ---------------------------------------------------------------------------
// MFMA kNN screen. Stride-5 uint4 LDS rows. 4 waves, i-tile 128; 3-pass fp16
// hi/lo; e = dot - sq_j/2 via augmented channel. Lane owns i-col lane&31;
// top-12 as u32 keys (umax/umin ladder, branch-light). Writes keys only.
// ---------------------------------------------------------------------------
__global__ __launch_bounds__(256) __attribute__((amdgpu_waves_per_eu(2))) void knn_kernel(
    const unsigned short* __restrict__ Xh, const unsigned short* __restrict__ Xl,
    const unsigned* __restrict__ S2, unsigned* __restrict__ PK)
{
    __shared__ uint4 lds[2560];   // 4 arrays (Ah,Al,Bh,Bl) x 128 rows x stride-5

    const int tid  = threadIdx.x;
    const int lane = tid & 63;
    const int w    = tid >> 6;
    const int l31  = lane & 31;
    const int h    = lane >> 5;
    const int bid  = blockIdx.x;
    const int b    = bid & 7;
    const int t2   = bid >> 3;
    const int itile = t2 >> 3;
    const int sp    = t2 & 7;
    const int i0    = itile * 128;
    const int g0 = (sp*25)/8, g1 = ((sp+1)*25)/8;
    const size_t rowb = (size_t)b * NPAD;

    unsigned t_k0=0,t_k1=0,t_k2=0,t_k3=0,t_k4=0,t_k5=0,
             t_k6=0,t_k7=0,t_k8=0,t_k9=0,t_k10=0,t_k11=0;

    for (int g = g0; g < g1; ++g){
        const int jg = g*128;
        f32x16 acc0 = ZERO16, acc1 = ZERO16, acc2 = ZERO16, acc3 = ZERO16;

        for (int kc = 0; kc < 6; ++kc){
            __syncthreads();
            #pragma unroll
            for (int rr = 0; rr < 8; ++rr){
                int u   = tid + rr*256;
                int arr = u >> 9;
                int rs  = (u >> 2) & 127;
                int seg = u & 3;
                int row = (arr < 2) ? (jg + rs) : (i0 + rs);
                const unsigned short* sptr = (arr & 1) ? Xl : Xh;
                uint4 v = *(const uint4*)&sptr[(rowb + row)*192 + kc*32 + seg*8];
                lds[arr*640 + rs*5 + seg] = v;
            }
            __syncthreads();
            #pragma unroll
            for (int ks = 0; ks < 2; ++ks){
                int kq  = ks*2 + h;
                int rb  = l31*5 + kq;
                f16x8 bh = __builtin_bit_cast(f16x8, lds[1280 + w*160 + rb]);
                f16x8 bl = __builtin_bit_cast(f16x8, lds[1920 + w*160 + rb]);
                f16x8 a0h = __builtin_bit_cast(f16x8, lds[      0 + rb]);
                f16x8 a0l = __builtin_bit_cast(f16x8, lds[640 +   0 + rb]);
                MF(acc0, a0h, bh) MF(acc0, a0l, bh) MF(acc0, a0h, bl)
                f16x8 a1h = __builtin_bit_cast(f16x8, lds[      160 + rb]);
                f16x8 a1l = __builtin_bit_cast(f16x8, lds[640 + 160 + rb]);
                MF(acc1, a1h, bh) MF(acc1, a1l, bh) MF(acc1, a1h, bl)
                f16x8 a2h = __builtin_bit_cast(f16x8, lds[      320 + rb]);
                f16x8 a2l = __builtin_bit_cast(f16x8, lds[640 + 320 + rb]);
                MF(acc2, a2h, bh) MF(acc2, a2l, bh) MF(acc2, a2h, bl)
                f16x8 a3h = __builtin_bit_cast(f16x8, lds[      480 + rb]);
                f16x8 a3l = __builtin_bit_cast(f16x8, lds[640 + 480 + rb]);
                MF(acc3, a3h, bh) MF(acc3, a3l, bh) MF(acc3, a3h, bl)
            }
        }

        // k=192 channel: A = -sq_j/2 (hi/lo), B = 1 at k-elem 0 (h==0 lanes)
        {
            unsigned m  = (h == 0) ? 0xFFFFFFFFu : 0u;
            unsigned om = 0x3C00u & m;
            f16x8 one = __builtin_bit_cast(f16x8, make_uint4(om, 0, 0, 0));
            unsigned s0 = S2[rowb + jg +  0 + l31];
            unsigned s1 = S2[rowb + jg + 32 + l31];
            unsigned s2 = S2[rowb + jg + 64 + l31];
            unsigned s3 = S2[rowb + jg + 96 + l31];
            f16x8 a;
            a = __builtin_bit_cast(f16x8, make_uint4((s0 & 0xFFFFu) & m, 0,0,0)); MF(acc0, a, one)
            a = __builtin_bit_cast(f16x8, make_uint4((s0 >> 16)     & m, 0,0,0)); MF(acc0, a, one)
            a = __builtin_bit_cast(f16x8, make_uint4((s1 & 0xFFFFu) & m, 0,0,0)); MF(acc1, a, one)
            a = __builtin_bit_cast(f16x8, make_uint4((s1 >> 16)     & m, 0,0,0)); MF(acc1, a, one)
            a = __builtin_bit_cast(f16x8, make_uint4((s2 & 0xFFFFu) & m, 0,0,0)); MF(acc2, a, one)
            a = __builtin_bit_cast(f16x8, make_uint4((s2 >> 16)     & m, 0,0,0)); MF(acc2, a, one)
            a = __builtin_bit_cast(f16x8, make_uint4((s3 & 0xFFFFu) & m, 0,0,0)); MF(acc3, a, one)
            a = __builtin_bit_cast(f16x8, make_uint4((s3 >> 16)     & m, 0,0,0)); MF(acc3, a, one)
        }

        INSACCK(acc0, 0)
        INSACCK(acc1, 1)
        INSACCK(acc2, 2)
        INSACCK(acc3, 3)
    }

    // merge lane pair (same i-col, disjoint j rows)
    #define MRGK(K) { unsigned ok_ = __shfl((int)(K), lane ^ 32, 64); \
                      if (lane < 32) { INSKEY((unsigned)ok_) } }
    MRGK(t_k0) MRGK(t_k1) MRGK(t_k2) MRGK(t_k3) MRGK(t_k4) MRGK(t_k5)
    MRGK(t_k6) MRGK(t_k7) MRGK(t_k8) MRGK(t_k9) MRGK(t_k10) MRGK(t_k11)

    if (lane < 32){
        size_t po = ((size_t)(t2*8 + b)*128 + (size_t)w*32 + l31)*12;
        PK[po+ 0] = t_k0;  PK[po+ 1] = t_k1;  PK[po+ 2] = t_k2;  PK[po+ 3] = t_k3;
        PK[po+ 4] = t_k4;  PK[po+ 5] = t_k5;  PK[po+ 6] = t_k6;  PK[po+ 7] = t_k7;
        PK[po+ 8] = t_k8;  PK[po+ 9] = t_k9;  PK[po+10] = t_k10; PK[po+11] = t_k11;
    }
}

// ---------------------------------------------------------------------------
// 8-way sorted key-list merge -> global approx top-12 -> exact fp32 rescore
// -> top-9 -> max-message. 16 rows/block.
// ---------------------------------------------------------------------------
__global__ __launch_bounds__(256) void merge_msg_kernel(
    const float* __restrict__ H, const float* __restrict__ SQf,
    const unsigned* __restrict__ PK, float* __restrict__ Hout)
{
    __shared__ float liX[16*196];
    __shared__ unsigned kv[1600];  // [16 rows][stride 100]: 8 lists x 12 keys
    __shared__ float cd[192];
    __shared__ int   cidx[192];
    __shared__ int   fidx[144];

    const int tid = threadIdx.x;
    const int bid = blockIdx.x;
    const int b  = bid / 196;
    const int i0 = (bid % 196) * 16;
    const int base = b * NPIX;

    // stage the 16 i-rows (first 192 cols of H)
    #pragma unroll
    for (int k = 0; k < 3; ++k){
        int f = tid + k*256;
        int r = f / 48, c4 = f % 48;
        *(float4*)&liX[r*196 + c4*4] = *(const float4*)&H[(size_t)(base + i0 + r)*384 + c4*4];
    }
    // stage candidate key lists
    if (tid < 128){
        int r = tid >> 3, sp = tid & 7;
        int i = i0 + r;
        size_t po = ((size_t)(((i>>7)*8 + sp)*8 + b)*128 + (i & 127))*12;
        #pragma unroll
        for (int q = 0; q < 3; ++q)
            *(uint4*)&kv[r*100 + sp*12 + q*4] = *(const uint4*)&PK[po + q*4];
    }
    __syncthreads();

    // per-row 8-way merge (lists sorted desc) -> top-12 candidate j's
    if (tid < 16){
        int r = tid;
        int h0=0,h1=0,h2=0,h3=0,h4=0,h5=0,h6=0,h7=0;
        #pragma unroll
        for (int p = 0; p < 12; ++p){
            unsigned bk = 0; int bs = 0;
#define HEADC(SP,HV) { \
            unsigned k_ = (HV < 12) ? kv[r*100 + SP*12 + HV] : 0u; \
            bool bt_ = k_ > bk; \
            bk = bt_? k_ : bk; bs = bt_? SP : bs; }
            HEADC(0,h0) HEADC(1,h1) HEADC(2,h2) HEADC(3,h3)
            HEADC(4,h4) HEADC(5,h5) HEADC(6,h6) HEADC(7,h7)
#undef HEADC
            cidx[r*12 + p] = 4095 - (int)(bk & 0xFFFu);
            h0 += (bs==0); h1 += (bs==1); h2 += (bs==2); h3 += (bs==3);
            h4 += (bs==4); h5 += (bs==5); h6 += (bs==6); h7 += (bs==7);
        }
    }
    __syncthreads();

    // exact fp32 rescore of the 12 candidates per row
    if (tid < 192){
        int r = tid / 12, p = tid - r*12;
        int j = cidx[r*12 + p];
        const float* hj = &H[(size_t)(base + j)*384];
        float dot = 0.f;
        #pragma unroll
        for (int q = 0; q < 48; ++q){
            float4 xv = *(const float4*)&liX[r*196 + q*4];
            float4 yv = *(const float4*)&hj[q*4];
            dot = fmaf(xv.x,yv.x, fmaf(xv.y,yv.y, fmaf(xv.z,yv.z, fmaf(xv.w,yv.w, dot))));
        }
        cd[r*12 + p] = SQf[base + j] - 2.f*dot;
    }
    __syncthreads();

    if (tid < 16){
        int r = tid;
        Top9 m; m.init();
        #pragma unroll
        for (int c = 0; c < 12; ++c) m.insert(cd[r*12 + c], cidx[r*12 + c]);
        fidx[r*9+0]=m.j0; fidx[r*9+1]=m.j1; fidx[r*9+2]=m.j2; fidx[r*9+3]=m.j3;
        fidx[r*9+4]=m.j4; fidx[r*9+5]=m.j5; fidx[r*9+6]=m.j6; fidx[r*9+7]=m.j7;
        fidx[r*9+8]=m.j8;
    }
    __syncthreads();

    int rr = tid >> 4, part = tid & 15;
    int ii = i0 + rr;
    int nbr[9];
    #pragma unroll
    for (int e = 0; e < 9; ++e) nbr[e] = fidx[rr*9 + e];
    const float* pi = H + (size_t)(base + ii)*384 + part*12;
    float* po = Hout + (size_t)(base + ii)*384 + 192 + part*12;
    #pragma unroll
    for (int q = 0; q < 3; ++q){
        float4 mv = make_float4(-FINF, -FINF, -FINF, -FINF);
        #pragma unroll
        for (int e = 0; e < 9; ++e){
            float4 v = *(const float4*)&H[(size_t)(base + nbr[e])*384 + part*12 + q*4];
            mv.x = fmaxf(mv.x, v.x); mv.y = fmaxf(mv.y, v.y);
            mv.z = fmaxf(mv.z, v.z); mv.w = fmaxf(mv.w, v.w);
        }
        float4 xi = *(const float4*)&pi[q*4];
        *(float4*)&po[q*4] = make_float4(mv.x - xi.x, mv.y - xi.y, mv.z - xi.z, mv.w - xi.w);
    }
}

extern "C" void kernel_launch(void* const* d_in, const int* in_sizes, int n_in,
                              void* d_out, int out_size, void* d_ws, size_t ws_size,
                              hipStream_t stream)
{
    const float* x  = (const float*)d_in[0];
    const float* W1 = (const float*)d_in[1];
    const float* b1 = (const float*)d_in[2];
    const float* s1 = (const float*)d_in[3];
    const float* W2 = (const float*)d_in[4];
    const float* b2 = (const float*)d_in[5];
    const float* s2 = (const float*)d_in[6];
    const float* Wg = (const float*)d_in[7];
    const float* bg = (const float*)d_in[8];
    const float* sg = (const float*)d_in[9];
    const float* W3 = (const float*)d_in[10];
    const float* b3 = (const float*)d_in[11];
    const float* s3 = (const float*)d_in[12];
    const float* W4 = (const float*)d_in[13];
    const float* b4 = (const float*)d_in[14];
    const float* s4 = (const float*)d_in[15];

    float* H  = (float*)d_ws;                         // [25088][384]
    float* T1 = H  + (size_t)25088*384;               // LL1 out; LL3 out later
    float* X2 = T1 + (size_t)25088*192;               // PK during knn/merge; graph-conv out later
    unsigned short* Xh = (unsigned short*)(X2 + (size_t)25088*192);  // [8][3200][192] fp16 hi
    unsigned short* Xl = Xh + (size_t)NB*NPAD*192;                   // fp16 lo
    unsigned* S2p = (unsigned*)(Xl + (size_t)NB*NPAD*192);           // [8][3200] packed -sq/2
    float* SQf = (float*)(S2p + (size_t)NB*NPAD);                    // [8][3136] fp32 sq
    unsigned* PK = (unsigned*)X2;                     // 1600*128*12 keys = 9.8 MB
    float* out = (float*)d_out;

    // ffn_lorentz #1
    ll_kernel<192, true , false, false, false><<<GRID_LL, 256, 0, stream>>>(x, 0,   W1, b1, s1, nullptr, nullptr, 0, T1, 192);
    ll_kernel<192, false, true , false, false><<<GRID_LL, 256, 0, stream>>>(T1, 192, W2, b2, s2, x,      nullptr, 0, H, 384);
    // graph conv
    conv_kernel<<<NB*NPAD/64, 256, 0, stream>>>(H, Xh, Xl, S2p, SQf);
    knn_kernel<<<GRID_KNN, 256, 0, stream>>>(Xh, Xl, S2p, PK);
    merge_msg_kernel<<<GRID_MSG, 256, 0, stream>>>(H, SQf, PK, H);
    ll_kernel<384, false, false, false, false><<<GRID_LL, 256, 0, stream>>>(H, 384,  Wg, bg, sg, nullptr, nullptr, 0, X2, 192);
    // ffn_lorentz #2 + final shortcut, transposed store
    ll_kernel<192, false, false, false, false><<<GRID_LL, 256, 0, stream>>>(X2, 192, W3, b3, s3, nullptr, nullptr, 0, T1, 192);
    ll_kernel<192, false, true , true , true ><<<GRID_LL, 256, 0, stream>>>(T1, 192, W4, b4, s4, x,      X2, 192, out, 0);
}

// Round 12
// 527.011 us; speedup vs baseline: 2.9744x; 1.2248x over previous
//
#include <hip/hip_runtime.h>
#include <math.h>

#define NB   8
#define NC   192
#define NPIX 3136
#define NPAD 3200
#define GRID_LL (NB*98)    // 784: M-tile 32
#define NIT  25
#define NSP  8
#define GRID_KNN (NB*NIT*NSP)   // 1600
#define GRID_MSG (NB*196)  // 1568
#define FINF 3.4e38f

typedef _Float16 f16x8 __attribute__((ext_vector_type(8)));
typedef float   f32x16 __attribute__((ext_vector_type(16)));

__device__ __forceinline__ float gelu_f(float x){
    float u = 0.7978845608028654f * (x + 0.044715f * x * x * x);
    return 0.5f * x * (1.0f + tanhf(u));
}

// ---------------- min-lex top9 (exact rescore) ----------------
#define LESS9(da,ia,db,ib) ((da) < (db) || ((da) == (db) && (ia) < (ib)))
#define CSW9(a,ia,b,ib) { bool sw_ = LESS9(b,ib,a,ia); float tf_=(a); int ti_=(ia); \
    (a) = sw_? (b) : (a); (ia) = sw_? (ib) : (ia); (b) = sw_? tf_ : (b); (ib) = sw_? ti_ : (ib); }

struct Top9 {
    float d0,d1,d2,d3,d4,d5,d6,d7,d8;
    int   j0,j1,j2,j3,j4,j5,j6,j7,j8;
    __device__ __forceinline__ void init(){
        d0=d1=d2=d3=d4=d5=d6=d7=d8=FINF;
        j0=j1=j2=j3=j4=j5=j6=j7=j8=0x7FFFFFFF;
    }
    __device__ __forceinline__ void insert(float nd, int ni){
        if (!LESS9(nd, ni, d8, j8)) return;
        d8 = nd; j8 = ni;
        CSW9(d7,j7,d8,j8); CSW9(d6,j6,d7,j7); CSW9(d5,j5,d6,j6); CSW9(d4,j4,d5,j5);
        CSW9(d3,j3,d4,j4); CSW9(d2,j2,d3,j3); CSW9(d1,j1,d2,j2); CSW9(d0,j0,d1,j1);
    }
};

// ---------------- u32-key top12 (knn screen) ----------------
__device__ __forceinline__ unsigned f2mono(float e){
    unsigned u = __float_as_uint(e);
    return u ^ ((unsigned)((int)u >> 31) | 0x80000000u);
}

#define CSK(a,b) { unsigned h_ = (a) > (b) ? (a) : (b); unsigned l_ = (a) > (b) ? (b) : (a); (a) = h_; (b) = l_; }
#define INSKEY(x_) if ((x_) > t_k11){ t_k11 = (x_); \
    CSK(t_k10,t_k11) CSK(t_k9,t_k10) CSK(t_k8,t_k9) CSK(t_k7,t_k8) \
    CSK(t_k6,t_k7) CSK(t_k5,t_k6) CSK(t_k4,t_k5) CSK(t_k3,t_k4) \
    CSK(t_k2,t_k3) CSK(t_k1,t_k2) CSK(t_k0,t_k1) }

#define KQ(A,Q) { \
    unsigned q0_ = (f2mono(A[4*(Q)+0]) & 0xFFFFF000u) | (unsigned)(jinvb_ - 8*(Q)    ); \
    unsigned q1_ = (f2mono(A[4*(Q)+1]) & 0xFFFFF000u) | (unsigned)(jinvb_ - 8*(Q) - 1); \
    unsigned q2_ = (f2mono(A[4*(Q)+2]) & 0xFFFFF000u) | (unsigned)(jinvb_ - 8*(Q) - 2); \
    unsigned q3_ = (f2mono(A[4*(Q)+3]) & 0xFFFFF000u) | (unsigned)(jinvb_ - 8*(Q) - 3); \
    unsigned qa_ = q0_ > q1_ ? q0_ : q1_; \
    unsigned qb_ = q2_ > q3_ ? q2_ : q3_; \
    unsigned qm_ = qa_ > qb_ ? qa_ : qb_; \
    if (qm_ > t_k11){ INSKEY(q0_) INSKEY(q1_) INSKEY(q2_) INSKEY(q3_) } }

#define INSACCK(A,JS) { int jinvb_ = 4095 - (jg + (JS)*32 + 4*h); \
    KQ(A,0) KQ(A,1) KQ(A,2) KQ(A,3) }

#define MF(ACC,AO,BO) ACC = __builtin_amdgcn_mfma_f32_32x32x16_f16(AO,BO,ACC,0,0,0);
#define ZERO16 {0,0,0,0,0,0,0,0,0,0,0,0,0,0,0,0}

// ---------------------------------------------------------------------------
// Weight transpose: WT[k][n] = W[n][k]. 32x32 tiles via LDS.
// ---------------------------------------------------------------------------
__global__ __launch_bounds__(256) void wt_kernel(
    const float* __restrict__ W1, const float* __restrict__ W2,
    const float* __restrict__ Wg, const float* __restrict__ W3,
    const float* __restrict__ W4,
    float* __restrict__ W1T, float* __restrict__ W2T, float* __restrict__ WgT,
    float* __restrict__ W3T, float* __restrict__ W4T)
{
    __shared__ float tile[32*33];
    int t = blockIdx.x;
    const float* src; float* dst; int Kin;
    if (t < 36)      { src = W1; dst = W1T; Kin = 192; }
    else if (t < 72) { src = W2; dst = W2T; Kin = 192; t -= 36; }
    else if (t < 144){ src = Wg; dst = WgT; Kin = 384; t -= 72; }
    else if (t < 180){ src = W3; dst = W3T; Kin = 192; t -= 144; }
    else             { src = W4; dst = W4T; Kin = 192; t -= 180; }
    int ntc = Kin >> 5;
    int tr = t / ntc, tc = t - tr*ntc;
    int tid = threadIdx.x;
    {
        int i = tid >> 3, j4 = (tid & 7)*4;
        float4 v = *(const float4*)&src[(size_t)(tr*32 + i)*Kin + tc*32 + j4];
        tile[i*33 + j4+0] = v.x; tile[i*33 + j4+1] = v.y;
        tile[i*33 + j4+2] = v.z; tile[i*33 + j4+3] = v.w;
    }
    __syncthreads();
    {
        int j = tid >> 3, i4 = (tid & 7)*4;
        float4 o = make_float4(tile[(i4+0)*33 + j], tile[(i4+1)*33 + j],
                               tile[(i4+2)*33 + j], tile[(i4+3)*33 + j]);
        *(float4*)&dst[(size_t)(tc*32 + j)*192 + tr*32 + i4] = o;
    }
}

// ---------------------------------------------------------------------------
// Fused GEMM + lorentz_linear, col-major activations.
// A planes: A0 for c<192, A1 for c>=192 (K=384). WT pre-transposed [K][192].
// Out col-major [b][192][n]; optional dual row-major Hrm write.
// ---------------------------------------------------------------------------
template<int K, bool DUAL, bool AX, bool AR>
__global__ __launch_bounds__(256, 4) void ll2_kernel(
    const float* __restrict__ A0, const float* __restrict__ A1,
    const float* __restrict__ WT, const float* __restrict__ bias,
    const float* __restrict__ sptr, const float* __restrict__ Xres,
    const float* __restrict__ Rcm,
    float* __restrict__ OutCM, float* __restrict__ Hrm)
{
    __shared__ float lA[32*36];    // [kk][mm]
    __shared__ float lW[32*196];   // [kk][nn]

    const int tid = threadIdx.x;
    const int tx = tid & 15, ty = tid >> 4;
    const int bid = blockIdx.x;
    const int b  = bid / 98;
    const int n0 = (bid % 98) * 32;

    float acc[2][12];
    #pragma unroll
    for (int mi = 0; mi < 2; ++mi)
        #pragma unroll
        for (int j = 0; j < 12; ++j) acc[mi][j] = 0.f;

    for (int kt = 0; kt < K/32; ++kt){
        // A stage: 32k x 32m, b128, gelu
        {
            int kk = tid >> 3;
            int m4 = (tid & 7) * 4;
            int c  = kt*32 + kk;
            const float* pl;
            if (K > 192 && c >= 192) pl = A1 + ((size_t)b*192 + (c - 192))*NPIX;
            else                     pl = A0 + ((size_t)b*192 + c)*NPIX;
            float4 v = *(const float4*)&pl[n0 + m4];
            v.x = gelu_f(v.x); v.y = gelu_f(v.y); v.z = gelu_f(v.z); v.w = gelu_f(v.w);
            *(float4*)&lA[kk*36 + m4] = v;
        }
        // W stage: 32k x 192n direct b128 copies from WT
        #pragma unroll
        for (int r = 0; r < 6; ++r){
            int e  = tid + r*256;
            int kk = e / 48;
            int c4 = (e - kk*48) * 4;
            float4 v = *(const float4*)&WT[(size_t)(kt*32 + kk)*192 + c4];
            *(float4*)&lW[kk*196 + c4] = v;
        }
        __syncthreads();
        #pragma unroll
        for (int kk = 0; kk < 32; ++kk){
            float2 a2 = *(const float2*)&lA[kk*36 + ty*2];
            float4 w0 = *(const float4*)&lW[kk*196 + tx*12];
            float4 w1 = *(const float4*)&lW[kk*196 + tx*12 + 4];
            float4 w2 = *(const float4*)&lW[kk*196 + tx*12 + 8];
            float aw[2]  = {a2.x, a2.y};
            float wv[12] = {w0.x,w0.y,w0.z,w0.w, w1.x,w1.y,w1.z,w1.w, w2.x,w2.y,w2.z,w2.w};
            #pragma unroll
            for (int mi = 0; mi < 2; ++mi)
                #pragma unroll
                for (int j = 0; j < 12; ++j)
                    acc[mi][j] = fmaf(aw[mi], wv[j], acc[mi][j]);
        }
        __syncthreads();
    }

    const int lane = tid & 63;
    float es = expf(sptr[0]);
    float bv[12];
    #pragma unroll
    for (int q = 0; q < 3; ++q){
        float4 t4 = *(const float4*)&bias[tx*12 + q*4];
        bv[q*4+0] = t4.x; bv[q*4+1] = t4.y; bv[q*4+2] = t4.z; bv[q*4+3] = t4.w;
    }
    #pragma unroll
    for (int mi = 0; mi < 2; ++mi){
        float part = 0.f;
        #pragma unroll
        for (int j = 0; j < 12; ++j){
            float y = acc[mi][j] + bv[j];
            acc[mi][j] = y;
            if (!(tx == 0 && j == 0)) part += y * y;
        }
        #pragma unroll
        for (int m = 1; m < 16; m <<= 1) part += __shfl_xor(part, m, 64);
        float y0   = __shfl(acc[mi][0], lane & 48, 64);
        float tval = es / (1.f + expf(-y0)) + 1.1f;
        float denom = fmaxf(part, 1e-8f);
        float sca  = (tval*tval - 1.f) / denom;
        float sqs  = sqrtf(sca);
        #pragma unroll
        for (int j = 0; j < 12; ++j){
            float o = acc[mi][j] * sqs;
            if (tx == 0 && j == 0) o = tval;
            acc[mi][j] = o;
        }
    }
    if (AX){
        #pragma unroll
        for (int j = 0; j < 12; ++j){
            int c = tx*12 + j;
            float2 xv = *(const float2*)&Xres[((size_t)b*192 + c)*NPIX + n0 + ty*2];
            acc[0][j] += xv.x; acc[1][j] += xv.y;
        }
    }
    if (AR){
        #pragma unroll
        for (int j = 0; j < 12; ++j){
            int c = tx*12 + j;
            float2 rv = *(const float2*)&Rcm[((size_t)b*192 + c)*NPIX + n0 + ty*2];
            acc[0][j] += rv.x; acc[1][j] += rv.y;
        }
    }
    #pragma unroll
    for (int j = 0; j < 12; ++j){
        int c = tx*12 + j;
        *(float2*)&OutCM[((size_t)b*192 + c)*NPIX + n0 + ty*2] = make_float2(acc[0][j], acc[1][j]);
    }
    if (DUAL){
        #pragma unroll
        for (int mi = 0; mi < 2; ++mi){
            #pragma unroll
            for (int q = 0; q < 3; ++q){
                float4 o = make_float4(acc[mi][q*4+0], acc[mi][q*4+1], acc[mi][q*4+2], acc[mi][q*4+3]);
                *(float4*)&Hrm[((size_t)b*NPIX + n0 + ty*2 + mi)*192 + tx*12 + q*4] = o;
            }
        }
    }
}

// ---------------------------------------------------------------------------
// conv: Hrm fp32 rows (stride 192) -> Xh/Xl fp16 hi/lo, S2 packed(-sq/2), SQf.
// ---------------------------------------------------------------------------
__device__ __forceinline__ unsigned pack2(float a, float b, unsigned &lo){
    union { _Float16 f; unsigned short u; } ha, hb, la, lb;
    ha.f = (_Float16)a; hb.f = (_Float16)b;
    float ra = a - (float)ha.f, rb = b - (float)hb.f;
    la.f = (_Float16)ra; lb.f = (_Float16)rb;
    lo = (unsigned)la.u | ((unsigned)lb.u << 16);
    return (unsigned)ha.u | ((unsigned)hb.u << 16);
}

__global__ __launch_bounds__(256) void conv_kernel(
    const float* __restrict__ H, unsigned short* __restrict__ Xh,
    unsigned short* __restrict__ Xl, unsigned* __restrict__ S2,
    float* __restrict__ SQf)
{
    const int tid = threadIdx.x;
    const int r = blockIdx.x*64 + (tid >> 2);
    const int b = r / NPAD, rl = r - b*NPAD;
    const int part = tid & 3;
    const size_t ob = ((size_t)b*NPAD + rl)*192 + part*48;

    if (rl < NPIX){
        const float* src = H + ((size_t)b*NPIX + rl)*192 + part*48;
        float s = 0.f;
        #pragma unroll
        for (int q = 0; q < 6; ++q){
            float4 v0 = *(const float4*)&src[q*8];
            float4 v1 = *(const float4*)&src[q*8 + 4];
            s = fmaf(v0.x,v0.x, fmaf(v0.y,v0.y, fmaf(v0.z,v0.z, fmaf(v0.w,v0.w, s))));
            s = fmaf(v1.x,v1.x, fmaf(v1.y,v1.y, fmaf(v1.z,v1.z, fmaf(v1.w,v1.w, s))));
            uint4 hv, lv;
            hv.x = pack2(v0.x, v0.y, lv.x);
            hv.y = pack2(v0.z, v0.w, lv.y);
            hv.z = pack2(v1.x, v1.y, lv.z);
            hv.w = pack2(v1.z, v1.w, lv.w);
            *(uint4*)&Xh[ob + q*8] = hv;
            *(uint4*)&Xl[ob + q*8] = lv;
        }
        s += __shfl_xor(s, 1, 64);
        s += __shfl_xor(s, 2, 64);
        if (part == 0){
            SQf[(size_t)b*NPIX + rl] = s;
            float s2 = -0.5f * s;
            union { _Float16 f; unsigned short u; } hh, ll;
            hh.f = (_Float16)s2;
            float rr = s2 - (float)hh.f;
            ll.f = (_Float16)rr;
            S2[(size_t)b*NPAD + rl] = (unsigned)hh.u | ((unsigned)ll.u << 16);
        }
    } else {
        uint4 z = make_uint4(0,0,0,0);
        #pragma unroll
        for (int q = 0; q < 6; ++q){
            *(uint4*)&Xh[ob + q*8] = z;
            *(uint4*)&Xl[ob + q*8] = z;
        }
        if (part == 0){
            union { _Float16 f; unsigned short u; } p;
            p.f = (_Float16)(-30000.0f);
            S2[(size_t)b*NPAD + rl] = (unsigned)p.u;
        }
    }
}

// ---------------------------------------------------------------------------
// MFMA kNN screen (unchanged from R11).
// ---------------------------------------------------------------------------
__global__ __launch_bounds__(256) __attribute__((amdgpu_waves_per_eu(2))) void knn_kernel(
    const unsigned short* __restrict__ Xh, const unsigned short* __restrict__ Xl,
    const unsigned* __restrict__ S2, unsigned* __restrict__ PK)
{
    __shared__ uint4 lds[2560];

    const int tid  = threadIdx.x;
    const int lane = tid & 63;
    const int w    = tid >> 6;
    const int l31  = lane & 31;
    const int h    = lane >> 5;
    const int bid  = blockIdx.x;
    const int b    = bid & 7;
    const int t2   = bid >> 3;
    const int itile = t2 >> 3;
    const int sp    = t2 & 7;
    const int i0    = itile * 128;
    const int g0 = (sp*25)/8, g1 = ((sp+1)*25)/8;
    const size_t rowb = (size_t)b * NPAD;

    unsigned t_k0=0,t_k1=0,t_k2=0,t_k3=0,t_k4=0,t_k5=0,
             t_k6=0,t_k7=0,t_k8=0,t_k9=0,t_k10=0,t_k11=0;

    for (int g = g0; g < g1; ++g){
        const int jg = g*128;
        f32x16 acc0 = ZERO16, acc1 = ZERO16, acc2 = ZERO16, acc3 = ZERO16;

        for (int kc = 0; kc < 6; ++kc){
            __syncthreads();
            #pragma unroll
            for (int rr = 0; rr < 8; ++rr){
                int u   = tid + rr*256;
                int arr = u >> 9;
                int rs  = (u >> 2) & 127;
                int seg = u & 3;
                int row = (arr < 2) ? (jg + rs) : (i0 + rs);
                const unsigned short* sptr = (arr & 1) ? Xl : Xh;
                uint4 v = *(const uint4*)&sptr[(rowb + row)*192 + kc*32 + seg*8];
                lds[arr*640 + rs*5 + seg] = v;
            }
            __syncthreads();
            #pragma unroll
            for (int ks = 0; ks < 2; ++ks){
                int kq  = ks*2 + h;
                int rb  = l31*5 + kq;
                f16x8 bh = __builtin_bit_cast(f16x8, lds[1280 + w*160 + rb]);
                f16x8 bl = __builtin_bit_cast(f16x8, lds[1920 + w*160 + rb]);
                f16x8 a0h = __builtin_bit_cast(f16x8, lds[      0 + rb]);
                f16x8 a0l = __builtin_bit_cast(f16x8, lds[640 +   0 + rb]);
                MF(acc0, a0h, bh) MF(acc0, a0l, bh) MF(acc0, a0h, bl)
                f16x8 a1h = __builtin_bit_cast(f16x8, lds[      160 + rb]);
                f16x8 a1l = __builtin_bit_cast(f16x8, lds[640 + 160 + rb]);
                MF(acc1, a1h, bh) MF(acc1, a1l, bh) MF(acc1, a1h, bl)
                f16x8 a2h = __builtin_bit_cast(f16x8, lds[      320 + rb]);
                f16x8 a2l = __builtin_bit_cast(f16x8, lds[640 + 320 + rb]);
                MF(acc2, a2h, bh) MF(acc2, a2l, bh) MF(acc2, a2h, bl)
                f16x8 a3h = __builtin_bit_cast(f16x8, lds[      480 + rb]);
                f16x8 a3l = __builtin_bit_cast(f16x8, lds[640 + 480 + rb]);
                MF(acc3, a3h, bh) MF(acc3, a3l, bh) MF(acc3, a3h, bl)
            }
        }

        {
            unsigned m  = (h == 0) ? 0xFFFFFFFFu : 0u;
            unsigned om = 0x3C00u & m;
            f16x8 one = __builtin_bit_cast(f16x8, make_uint4(om, 0, 0, 0));
            unsigned s0 = S2[rowb + jg +  0 + l31];
            unsigned s1 = S2[rowb + jg + 32 + l31];
            unsigned s2 = S2[rowb + jg + 64 + l31];
            unsigned s3 = S2[rowb + jg + 96 + l31];
            f16x8 a;
            a = __builtin_bit_cast(f16x8, make_uint4((s0 & 0xFFFFu) & m, 0,0,0)); MF(acc0, a, one)
            a = __builtin_bit_cast(f16x8, make_uint4((s0 >> 16)     & m, 0,0,0)); MF(acc0, a, one)
            a = __builtin_bit_cast(f16x8, make_uint4((s1 & 0xFFFFu) & m, 0,0,0)); MF(acc1, a, one)
            a = __builtin_bit_cast(f16x8, make_uint4((s1 >> 16)     & m, 0,0,0)); MF(acc1, a, one)
            a = __builtin_bit_cast(f16x8, make_uint4((s2 & 0xFFFFu) & m, 0,0,0)); MF(acc2, a, one)
            a = __builtin_bit_cast(f16x8, make_uint4((s2 >> 16)     & m, 0,0,0)); MF(acc2, a, one)
            a = __builtin_bit_cast(f16x8, make_uint4((s3 & 0xFFFFu) & m, 0,0,0)); MF(acc3, a, one)
            a = __builtin_bit_cast(f16x8, make_uint4((s3 >> 16)     & m, 0,0,0)); MF(acc3, a, one)
        }

        INSACCK(acc0, 0)
        INSACCK(acc1, 1)
        INSACCK(acc2, 2)
        INSACCK(acc3, 3)
    }

    #define MRGK(Kk) { unsigned ok_ = __shfl((int)(Kk), lane ^ 32, 64); \
                      if (lane < 32) { INSKEY((unsigned)ok_) } }
    MRGK(t_k0) MRGK(t_k1) MRGK(t_k2) MRGK(t_k3) MRGK(t_k4) MRGK(t_k5)
    MRGK(t_k6) MRGK(t_k7) MRGK(t_k8) MRGK(t_k9) MRGK(t_k10) MRGK(t_k11)

    if (lane < 32){
        size_t po = ((size_t)(t2*8 + b)*128 + (size_t)w*32 + l31)*12;
        PK[po+ 0] = t_k0;  PK[po+ 1] = t_k1;  PK[po+ 2] = t_k2;  PK[po+ 3] = t_k3;
        PK[po+ 4] = t_k4;  PK[po+ 5] = t_k5;  PK[po+ 6] = t_k6;  PK[po+ 7] = t_k7;
        PK[po+ 8] = t_k8;  PK[po+ 9] = t_k9;  PK[po+10] = t_k10; PK[po+11] = t_k11;
    }
}

// ---------------------------------------------------------------------------
// 8-way key merge -> top-12 -> exact fp32 rescore -> top-9 -> max-message.
// Hrm stride 192; msg written COL-MAJOR to Msg [b][192][n].
// ---------------------------------------------------------------------------
__global__ __launch_bounds__(256) void merge_msg_kernel(
    const float* __restrict__ H, const float* __restrict__ SQf,
    const unsigned* __restrict__ PK, float* __restrict__ Msg)
{
    __shared__ float liX[16*196];
    __shared__ unsigned kv[1600];
    __shared__ float cd[192];
    __shared__ int   cidx[192];
    __shared__ int   fidx[144];

    const int tid = threadIdx.x;
    const int bid = blockIdx.x;
    const int b  = bid / 196;
    const int i0 = (bid % 196) * 16;
    const int base = b * NPIX;

    #pragma unroll
    for (int k = 0; k < 3; ++k){
        int f = tid + k*256;
        int r = f / 48, c4 = f % 48;
        *(float4*)&liX[r*196 + c4*4] = *(const float4*)&H[(size_t)(base + i0 + r)*192 + c4*4];
    }
    if (tid < 128){
        int r = tid >> 3, sp = tid & 7;
        int i = i0 + r;
        size_t po = ((size_t)(((i>>7)*8 + sp)*8 + b)*128 + (i & 127))*12;
        #pragma unroll
        for (int q = 0; q < 3; ++q)
            *(uint4*)&kv[r*100 + sp*12 + q*4] = *(const uint4*)&PK[po + q*4];
    }
    __syncthreads();

    if (tid < 16){
        int r = tid;
        int h0=0,h1=0,h2=0,h3=0,h4=0,h5=0,h6=0,h7=0;
        #pragma unroll
        for (int p = 0; p < 12; ++p){
            unsigned bk = 0; int bs = 0;
#define HEADC(SP,HV) { \
            unsigned k_ = (HV < 12) ? kv[r*100 + SP*12 + HV] : 0u; \
            bool bt_ = k_ > bk; \
            bk = bt_? k_ : bk; bs = bt_? SP : bs; }
            HEADC(0,h0) HEADC(1,h1) HEADC(2,h2) HEADC(3,h3)
            HEADC(4,h4) HEADC(5,h5) HEADC(6,h6) HEADC(7,h7)
#undef HEADC
            cidx[r*12 + p] = 4095 - (int)(bk & 0xFFFu);
            h0 += (bs==0); h1 += (bs==1); h2 += (bs==2); h3 += (bs==3);
            h4 += (bs==4); h5 += (bs==5); h6 += (bs==6); h7 += (bs==7);
        }
    }
    __syncthreads();

    if (tid < 192){
        int r = tid / 12, p = tid - r*12;
        int j = cidx[r*12 + p];
        const float* hj = &H[(size_t)(base + j)*192];
        float dot = 0.f;
        #pragma unroll
        for (int q = 0; q < 48; ++q){
            float4 xv = *(const float4*)&liX[r*196 + q*4];
            float4 yv = *(const float4*)&hj[q*4];
            dot = fmaf(xv.x,yv.x, fmaf(xv.y,yv.y, fmaf(xv.z,yv.z, fmaf(xv.w,yv.w, dot))));
        }
        cd[r*12 + p] = SQf[base + j] - 2.f*dot;
    }
    __syncthreads();

    if (tid < 16){
        int r = tid;
        Top9 m; m.init();
        #pragma unroll
        for (int c = 0; c < 12; ++c) m.insert(cd[r*12 + c], cidx[r*12 + c]);
        fidx[r*9+0]=m.j0; fidx[r*9+1]=m.j1; fidx[r*9+2]=m.j2; fidx[r*9+3]=m.j3;
        fidx[r*9+4]=m.j4; fidx[r*9+5]=m.j5; fidx[r*9+6]=m.j6; fidx[r*9+7]=m.j7;
        fidx[r*9+8]=m.j8;
    }
    __syncthreads();

    // msg col-major: rr = tid&15 (row), part = tid>>4 (12-col chunk)
    int rr = tid & 15, part = tid >> 4;
    int ii = i0 + rr;
    int nbr[9];
    #pragma unroll
    for (int e = 0; e < 9; ++e) nbr[e] = fidx[rr*9 + e];
    #pragma unroll
    for (int q = 0; q < 3; ++q){
        float4 mv = make_float4(-FINF, -FINF, -FINF, -FINF);
        #pragma unroll
        for (int e = 0; e < 9; ++e){
            float4 v = *(const float4*)&H[(size_t)(base + nbr[e])*192 + part*12 + q*4];
            mv.x = fmaxf(mv.x, v.x); mv.y = fmaxf(mv.y, v.y);
            mv.z = fmaxf(mv.z, v.z); mv.w = fmaxf(mv.w, v.w);
        }
        float4 xi = *(const float4*)&liX[rr*196 + part*12 + q*4];
        float m0 = mv.x - xi.x, m1 = mv.y - xi.y, m2 = mv.z - xi.z, m3 = mv.w - xi.w;
        int c = part*12 + q*4;
        Msg[((size_t)b*192 + c+0)*NPIX + ii] = m0;
        Msg[((size_t)b*192 + c+1)*NPIX + ii] = m1;
        Msg[((size_t)b*192 + c+2)*NPIX + ii] = m2;
        Msg[((size_t)b*192 + c+3)*NPIX + ii] = m3;
    }
}

extern "C" void kernel_launch(void* const* d_in, const int* in_sizes, int n_in,
                              void* d_out, int out_size, void* d_ws, size_t ws_size,
                              hipStream_t stream)
{
    const float* x  = (const float*)d_in[0];
    const float* W1 = (const float*)d_in[1];
    const float* b1 = (const float*)d_in[2];
    const float* s1 = (const float*)d_in[3];
    const float* W2 = (const float*)d_in[4];
    const float* b2 = (const float*)d_in[5];
    const float* s2 = (const float*)d_in[6];
    const float* Wg = (const float*)d_in[7];
    const float* bg = (const float*)d_in[8];
    const float* sg = (const float*)d_in[9];
    const float* W3 = (const float*)d_in[10];
    const float* b3 = (const float*)d_in[11];
    const float* s3 = (const float*)d_in[12];
    const float* W4 = (const float*)d_in[13];
    const float* b4 = (const float*)d_in[14];
    const float* s4 = (const float*)d_in[15];

    const size_t PL = (size_t)25088*192;              // plane-set size (4.82M floats)
    float* Hrm  = (float*)d_ws;                       // row-major xn1 [25088][192]
    float* X1cm = Hrm  + PL;                          // xn1 col-major
    float* T1cm = X1cm + PL;                          // LL1/LL3 out col-major
    float* X2cm = T1cm + PL;                          // LLg out col-major; PK alias
    float* MXr  = X2cm + PL;                          // Xh/Xl fp16 -> later Msg col-major
    unsigned short* Xh = (unsigned short*)MXr;
    unsigned short* Xl = Xh + (size_t)NB*NPAD*192;
    float* Msg = MXr;                                 // aliases Xh/Xl after knn
    unsigned* S2p = (unsigned*)(MXr + (size_t)NB*NPAD*192/2*2);  // = MXr + 4915200
    float* SQf = (float*)(S2p + (size_t)NB*NPAD);
    float* W1T = SQf + (size_t)NB*NPIX;
    float* W2T = W1T + 36864;
    float* WgT = W2T + 36864;
    float* W3T = WgT + 73728;
    float* W4T = W3T + 36864;
    unsigned* PK = (unsigned*)X2cm;                   // 2.46M u32, consumed before LLg
    float* out = (float*)d_out;

    wt_kernel<<<216, 256, 0, stream>>>(W1, W2, Wg, W3, W4, W1T, W2T, WgT, W3T, W4T);
    // ffn_lorentz #1
    ll2_kernel<192, false, false, false><<<GRID_LL, 256, 0, stream>>>(x,    x,    W1T, b1, s1, nullptr, nullptr, T1cm, nullptr);
    ll2_kernel<192, true , true , false><<<GRID_LL, 256, 0, stream>>>(T1cm, T1cm, W2T, b2, s2, x,       nullptr, X1cm, Hrm);
    // graph conv
    conv_kernel<<<NB*NPAD/64, 256, 0, stream>>>(Hrm, Xh, Xl, S2p, SQf);
    knn_kernel<<<GRID_KNN, 256, 0, stream>>>(Xh, Xl, S2p, PK);
    merge_msg_kernel<<<GRID_MSG, 256, 0, stream>>>(Hrm, SQf, PK, Msg);
    ll2_kernel<384, false, false, false><<<GRID_LL, 256, 0, stream>>>(X1cm, Msg,  WgT, bg, sg, nullptr, nullptr, X2cm, nullptr);
    // ffn_lorentz #2 + final shortcut (output is col-major = (B,C,H,W) native)
    ll2_kernel<192, false, false, false><<<GRID_LL, 256, 0, stream>>>(X2cm, X2cm, W3T, b3, s3, nullptr, nullptr, T1cm, nullptr);
    ll2_kernel<192, false, true , true ><<<GRID_LL, 256, 0, stream>>>(T1cm, T1cm, W4T, b4, s4, x,       X2cm,    out,  nullptr);
}